// Round 4
// baseline (349.217 us; speedup 1.0000x reference)
//
#include <hip/hip_runtime.h>

#define HW 3600
#define PADR 3712            // 29*128, zero-padded rows in transposed bf16 buffers
#define NF4 900              // float4 per x row
#define CAP 131072
#define KSEL 100
#define NT 58                // 64-col tiles (3712/64)
typedef unsigned long long U64;

using short8  = __attribute__((ext_vector_type(8))) short;
using float4v = __attribute__((ext_vector_type(4))) float;

// monotone map: float -> u32 preserving order for all finite values
__device__ __forceinline__ unsigned monof(float f) {
    unsigned b = __float_as_uint(f);
    return (b & 0x80000000u) ? ~b : (b | 0x80000000u);
}
__device__ __forceinline__ float unmonof(unsigned m) {
    return __uint_as_float((m & 0x80000000u) ? (m ^ 0x80000000u) : ~m);
}
__device__ __forceinline__ unsigned short f2bf(float f) {   // RNE
    unsigned b = __float_as_uint(f);
    return (unsigned short)((b + 0x7FFFu + ((b >> 16) & 1u)) >> 16);
}
__device__ __forceinline__ float bf2f(unsigned short h) {
    return __uint_as_float(((unsigned)h) << 16);
}

// ---- Pass 0: convert x (b,d,l) -> transposed split-bf16 hiT/loT (b,l,d) ----
__global__ __launch_bounds__(256) void conv_k(
    const float* __restrict__ x,
    unsigned short* __restrict__ hiT, unsigned short* __restrict__ loT)
{
    int b = blockIdx.z, l0 = blockIdx.x * 64, d0 = blockIdx.y * 64;
    __shared__ float t[64][65];
    int tid = threadIdx.x;
#pragma unroll
    for (int r = 0; r < 4; r++) {
        int idx = tid + 256 * r;              // 1024 float4 slots
        int d = idx >> 4, lq = idx & 15;
        int l = l0 + lq * 4;
        const float* src = x + ((size_t)b * 128 + d0 + d) * HW;
        float4 v;
        if (l + 3 < HW) v = *(const float4*)(src + l);
        else {
            v.x = (l     < HW) ? src[l]     : 0.f;
            v.y = (l + 1 < HW) ? src[l + 1] : 0.f;
            v.z = (l + 2 < HW) ? src[l + 2] : 0.f;
            v.w = (l + 3 < HW) ? src[l + 3] : 0.f;
        }
        t[lq * 4 + 0][d] = v.x; t[lq * 4 + 1][d] = v.y;
        t[lq * 4 + 2][d] = v.z; t[lq * 4 + 3][d] = v.w;
    }
    __syncthreads();
#pragma unroll
    for (int r = 0; r < 2; r++) {
        int idx = tid + 256 * r;              // 512 chunks of 8 bf16
        int l = idx >> 3, dq = idx & 7;
        unsigned hp[4], lp[4];
#pragma unroll
        for (int j = 0; j < 4; j++) {
            float f0 = t[l][dq * 8 + 2 * j], f1 = t[l][dq * 8 + 2 * j + 1];
            unsigned short h0 = f2bf(f0), h1 = f2bf(f1);
            unsigned short g0 = f2bf(f0 - bf2f(h0)), g1 = f2bf(f1 - bf2f(h1));
            hp[j] = (unsigned)h0 | ((unsigned)h1 << 16);
            lp[j] = (unsigned)g0 | ((unsigned)g1 << 16);
        }
        size_t o = ((size_t)b * PADR + l0 + l) * 128 + d0 + dq * 8;
        *(uint4*)(hiT + o) = make_uint4(hp[0], hp[1], hp[2], hp[3]);
        *(uint4*)(loT + o) = make_uint4(lp[0], lp[1], lp[2], lp[3]);
    }
}

// ---- Pass A: LDS-free direct-MFMA GEMM -> den sums, rowmax, per-tile maxv --
// A and B fragments load straight from global ([row][k] layout matches the
// 16x16x32 bf16 fragment: lane m -> row, quad q -> k-chunk). No K-loop
// barriers, no staging VALU, no LDS bank conflicts.
__global__ __launch_bounds__(256) void gemm_direct_k(
    const unsigned short* __restrict__ hiT, const unsigned short* __restrict__ loT,
    float* __restrict__ den_row, float* __restrict__ den_col,
    U64* __restrict__ rowmax, float* __restrict__ maxvt)
{
    const int batch = blockIdx.z;
    const unsigned short* Ah = hiT + (size_t)batch * PADR * 128;
    const unsigned short* Al = loT + (size_t)batch * PADR * 128;
    const unsigned short* Bh = hiT + (size_t)(batch + 4) * PADR * 128;
    const unsigned short* Bl = loT + (size_t)(batch + 4) * PADR * 128;

    __shared__ float rowsumS[128], colsumS[128];
    __shared__ U64 rowmaxS[128];

    const int tid = threadIdx.x;
    const int lane = tid & 63, w = tid >> 6;
    const int wr = w >> 1, wc = w & 1;
    const int m = lane & 15, q = lane >> 4;

    if (tid < 128) { rowsumS[tid] = 0.f; colsumS[tid] = 0.f; rowmaxS[tid] = 0ull; }
    __syncthreads();

    const int lbw = blockIdx.y * 128 + wr * 64;
    const int sbw = blockIdx.x * 128 + wc * 64;

    const unsigned short* pAh[4]; const unsigned short* pAl[4];
    const unsigned short* pBh[4]; const unsigned short* pBl[4];
#pragma unroll
    for (int t = 0; t < 4; t++) {
        size_t ao = (size_t)(lbw + t * 16 + m) * 128 + q * 8;
        size_t bo = (size_t)(sbw + t * 16 + m) * 128 + q * 8;
        pAh[t] = Ah + ao; pAl[t] = Al + ao;
        pBh[t] = Bh + bo; pBl[t] = Bl + bo;
    }

    float4v acc[4][4];
#pragma unroll
    for (int i = 0; i < 4; i++)
#pragma unroll
        for (int j = 0; j < 4; j++) acc[i][j] = (float4v){0.f, 0.f, 0.f, 0.f};

#pragma unroll
    for (int k0 = 0; k0 < 4; k0++) {
        short8 ah[4], al[4], bh[4], bl[4];
#pragma unroll
        for (int t = 0; t < 4; t++) {
            ah[t] = *(const short8*)(pAh[t] + k0 * 32);
            al[t] = *(const short8*)(pAl[t] + k0 * 32);
            bh[t] = *(const short8*)(pBh[t] + k0 * 32);
            bl[t] = *(const short8*)(pBl[t] + k0 * 32);
        }
#pragma unroll
        for (int mt = 0; mt < 4; mt++)
#pragma unroll
            for (int nt = 0; nt < 4; nt++) {
                acc[mt][nt] = __builtin_amdgcn_mfma_f32_16x16x32_bf16(ah[mt], bh[nt], acc[mt][nt], 0, 0, 0);
                acc[mt][nt] = __builtin_amdgcn_mfma_f32_16x16x32_bf16(ah[mt], bl[nt], acc[mt][nt], 0, 0, 0);
                acc[mt][nt] = __builtin_amdgcn_mfma_f32_16x16x32_bf16(al[mt], bh[nt], acc[mt][nt], 0, 0, 0);
            }
    }

    // ---- epilogue: stats only ----
    float colpart[4] = {0.f, 0.f, 0.f, 0.f};
    float rowpart[4][4];
    U64   rowmk[4][4];
#pragma unroll
    for (int i = 0; i < 4; i++)
#pragma unroll
        for (int r = 0; r < 4; r++) { rowpart[i][r] = 0.f; rowmk[i][r] = 0ull; }

#pragma unroll
    for (int mt = 0; mt < 4; mt++)
#pragma unroll
        for (int nt = 0; nt < 4; nt++) {
            int s = sbw + nt * 16 + m;
            bool sv = (s < HW);
#pragma unroll
            for (int r = 0; r < 4; r++) {
                int l = lbw + mt * 16 + q * 4 + r;
                float v = acc[mt][nt][r] * 0.078125f;   // 1/(128*0.1)
                float e = __expf(v);
                if (sv) {
                    rowpart[mt][r] += e;
                    U64 pk = ((U64)monof(v) << 32) | (unsigned)s;
                    if (pk > rowmk[mt][r]) rowmk[mt][r] = pk;
                }
                if (l < HW) colpart[nt] += e;
            }
        }
    const int ct = blockIdx.x * 2 + wc;     // this wave's 64-col tile index
#pragma unroll
    for (int mt = 0; mt < 4; mt++)
#pragma unroll
        for (int r = 0; r < 4; r++) {
            float v = rowpart[mt][r];
            U64 pk = rowmk[mt][r];
#pragma unroll
            for (int off = 1; off < 16; off <<= 1) {
                v += __shfl_xor(v, off);
                U64 o = __shfl_xor(pk, off);
                if (o > pk) pk = o;
            }
            if (m == 0) {
                int lr = wr * 64 + mt * 16 + q * 4 + r;
                atomicAdd(&rowsumS[lr], v);
                atomicMax(&rowmaxS[lr], pk);
                int rowA = lbw + mt * 16 + q * 4 + r;
                if (rowA < HW)
                    maxvt[((size_t)batch * NT + ct) * PADR + rowA] =
                        unmonof((unsigned)(pk >> 32));   // NaN if no valid col -> pruned
            }
        }
#pragma unroll
    for (int nt = 0; nt < 4; nt++) {
        float v = colpart[nt];
        v += __shfl_xor(v, 16);
        v += __shfl_xor(v, 32);
        if (q == 0) atomicAdd(&colsumS[wc * 64 + nt * 16 + m], v);
    }
    __syncthreads();
    if (tid < 128) {
        int l = blockIdx.y * 128 + tid;
        if (l < HW) {
            atomicAdd(&den_row[(size_t)batch * HW + l], rowsumS[tid]);
            atomicMax(&rowmax[(size_t)batch * HW + l], rowmaxS[tid]);
        }
        int s = blockIdx.x * 128 + tid;
        if (s < HW) atomicAdd(&den_col[(size_t)batch * HW + s], colsumS[tid]);
    }
}

// ---- Pass B: logs, per-tile min lnc, exact tau via 32-bit binary search ----
__global__ __launch_bounds__(256) void prep_k(
    const float* __restrict__ den_row, const float* __restrict__ den_col,
    const U64* __restrict__ rowmax,
    float* __restrict__ lnDr, float* __restrict__ lnDc,
    float* __restrict__ minlnc, float* __restrict__ tau)
{
    const int batch = blockIdx.z;
    const int tid = threadIdx.x;
    __shared__ float ldrS[HW];
    __shared__ float lncS[HW];
    __shared__ unsigned keyS[HW];
    __shared__ unsigned wcntS[4];
    __shared__ unsigned tmS;

    for (int i = tid; i < HW; i += 256) {
        float ldr = __logf(den_row[(size_t)batch * HW + i]);
        float ldc = __logf(den_col[(size_t)batch * HW + i]);
        lnDr[(size_t)batch * HW + i] = ldr;
        lnDc[(size_t)batch * HW + i] = ldc;
        ldrS[i] = ldr; lncS[i] = ldc;
    }
    if (tid == 0) tmS = 0u;
    __syncthreads();

    if (tid < NT) {      // per-64-col-tile min of lnc (tile 57: empty -> +inf)
        float mn = 3.4e38f;
        int s0 = tid * 64, s1 = s0 + 64; if (s1 > HW) s1 = HW;
        for (int s = s0; s < s1; s++) mn = fminf(mn, lncS[s]);
        minlnc[batch * NT + tid] = mn;
    }
    for (int i = tid; i < HW; i += 256) {
        U64 rm = rowmax[(size_t)batch * HW + i];
        float mv = unmonof((unsigned)(rm >> 32));
        unsigned col = (unsigned)(rm & 0xffffffffu);
        keyS[i] = monof(2.0f * mv - ldrS[i] - lncS[col]);
    }
    __syncthreads();

    // binary search: largest thr with count(keyS >= thr) >= KSEL == 100th-largest
    for (int bit = 31; bit >= 0; bit--) {
        unsigned candm = tmS | (1u << bit);
        unsigned c = 0;
        for (int i = tid; i < HW; i += 256) c += (keyS[i] >= candm) ? 1u : 0u;
#pragma unroll
        for (int off = 1; off < 64; off <<= 1) c += __shfl_xor(c, off);
        if ((tid & 63) == 0) wcntS[tid >> 6] = c;
        __syncthreads();
        if (tid == 0) {
            unsigned tc = wcntS[0] + wcntS[1] + wcntS[2] + wcntS[3];
            if (tc >= (unsigned)KSEL) tmS = candm;
        }
        __syncthreads();
    }
    // champions are a subset of all keys => this is <= the true 100th key.
    // slack covers cross-kernel FP-contraction drift; only ADDS candidates.
    if (tid == 0) tau[batch] = unmonof(tmS) - 1e-4f;
}

// ---- Pass C: build (row, 64-col-tile) pair list from maxvt bound -----------
__global__ __launch_bounds__(256) void pairs_k(
    const float* __restrict__ maxvt, const float* __restrict__ lnDr,
    const float* __restrict__ minlnc, const float* __restrict__ tau,
    int* __restrict__ pairrows, int* __restrict__ paircnt)
{
    const int batch = blockIdx.z, t = blockIdx.x;
    const float tv = tau[batch] - 1e-4f;      // extra margin on the bound test
    const float ml = minlnc[batch * NT + t];
    const float* mv = maxvt + ((size_t)batch * NT + t) * PADR;
    const float* ldr = lnDr + (size_t)batch * HW;
    int* pr = pairrows + ((size_t)batch * NT + t) * PADR;
    for (int r = threadIdx.x; r < HW; r += 256) {
        float b = 2.0f * mv[r] - ldr[r] - ml;   // NaN compares false -> skip
        if (b >= tv) {
            int p = atomicAdd(&paircnt[batch * NT + t], 1);
            pr[p] = r;
        }
    }
}

// ---- Pass D: recompute surviving pairs (bit-identical MFMA chain), collect -
__global__ __launch_bounds__(256) void recollect_k(
    const unsigned short* __restrict__ hiT, const unsigned short* __restrict__ loT,
    const float* __restrict__ lnDr, const float* __restrict__ lnDc,
    const float* __restrict__ tau, const int* __restrict__ pairrows,
    const int* __restrict__ paircnt, uint2* __restrict__ cand,
    int* __restrict__ cnt)
{
    const int batch = blockIdx.z, t = blockIdx.y;
    const int pc = paircnt[batch * NT + t];
    const int p0 = blockIdx.x * 16;
    if (p0 >= pc) return;
    const float tv = tau[batch];

    __shared__ int rowS[16];
    __shared__ float ldrS[16];
    const int tid = threadIdx.x;
    if (tid < 16) {
        int ri = p0 + tid;
        int row = (ri < pc) ? pairrows[((size_t)batch * NT + t) * PADR + ri] : HW;
        rowS[tid] = row;    // row HW..: zero pad rows, guarded at emit
        ldrS[tid] = (ri < pc) ? lnDr[(size_t)batch * HW + row] : 0.f;
    }
    __syncthreads();

    const unsigned short* Ah = hiT + (size_t)batch * PADR * 128;
    const unsigned short* Al = loT + (size_t)batch * PADR * 128;
    const unsigned short* Bh = hiT + (size_t)(batch + 4) * PADR * 128;
    const unsigned short* Bl = loT + (size_t)(batch + 4) * PADR * 128;

    const int lane = tid & 63, w = tid >> 6;
    const int m = lane & 15, q = lane >> 4;
    const size_t ao = (size_t)rowS[m] * 128 + q * 8;
    const int col = t * 64 + w * 16 + m;      // < PADR always
    const size_t bo = (size_t)col * 128 + q * 8;

    float4v acc = (float4v){0.f, 0.f, 0.f, 0.f};
#pragma unroll
    for (int k0 = 0; k0 < 4; k0++) {
        short8 ah = *(const short8*)(Ah + ao + k0 * 32);
        short8 al = *(const short8*)(Al + ao + k0 * 32);
        short8 bh = *(const short8*)(Bh + bo + k0 * 32);
        short8 bl = *(const short8*)(Bl + bo + k0 * 32);
        acc = __builtin_amdgcn_mfma_f32_16x16x32_bf16(ah, bh, acc, 0, 0, 0);
        acc = __builtin_amdgcn_mfma_f32_16x16x32_bf16(ah, bl, acc, 0, 0, 0);
        acc = __builtin_amdgcn_mfma_f32_16x16x32_bf16(al, bh, acc, 0, 0, 0);
    }
    if (col < HW) {
        float ldc = lnDc[(size_t)batch * HW + col];
#pragma unroll
        for (int r = 0; r < 4; r++) {
            int ri = q * 4 + r;
            if (p0 + ri >= pc) continue;
            float v = acc[r] * 0.078125f;
            float tt = 2.0f * v - ldrS[ri] - ldc;
            if (tt >= tv) {
                int p = atomicAdd(&cnt[batch], 1);
                if (p < CAP)
                    cand[(size_t)batch * CAP + p] =
                        make_uint2(monof(tt), (unsigned)(rowS[ri] * HW + col));
            }
        }
    }
}

// ---- Pass E: exact top-100 via 64-bit key binary search + rank, fold W -----
__global__ __launch_bounds__(256) void select_k(
    const uint2* __restrict__ cand, const int* __restrict__ cnt,
    const float* __restrict__ W,
    float* __restrict__ C0, float* __restrict__ C1,
    float* __restrict__ Sx, float* __restrict__ Sy)
{
    const int batch = blockIdx.z;
    const int tid = threadIdx.x;
    const uint2* cb = cand + (size_t)batch * CAP;
    int M = cnt[batch]; if (M > CAP) M = CAP;

    __shared__ uint2 lc[6144];
    __shared__ unsigned wcntS[4];
    __shared__ U64 tmS;
    __shared__ U64 selS[128];
    __shared__ int scS;
    __shared__ int topiS[KSEL];
    __shared__ float cx0S[KSEL], cy0S[KSEL], cx1S[KSEL], cy1S[KSEL];

    const bool useL = (M <= 6144);
    if (useL) for (int i = tid; i < M; i += 256) lc[i] = cb[i];
    if (tid == 0) { tmS = 0ull; scS = 0; }
    __syncthreads();

    // key = (mono_t << 32) | ~idx : unique; max-first = largest t, lowest idx
    for (int bit = 63; bit >= 0; bit--) {
        U64 candk = tmS | (1ull << bit);
        unsigned c = 0;
        for (int i = tid; i < M; i += 256) {
            uint2 e = useL ? lc[i] : cb[i];
            U64 key = ((U64)e.x << 32) | (unsigned)(~e.y);
            c += (key >= candk) ? 1u : 0u;
        }
#pragma unroll
        for (int off = 1; off < 64; off <<= 1) c += __shfl_xor(c, off);
        if ((tid & 63) == 0) wcntS[tid >> 6] = c;
        __syncthreads();
        if (tid == 0) {
            unsigned tc = wcntS[0] + wcntS[1] + wcntS[2] + wcntS[3];
            if (tc >= (unsigned)KSEL) tmS = candk;
        }
        __syncthreads();
    }
    U64 thr = tmS;   // exactly the 100th-largest key (keys unique)
    for (int i = tid; i < M; i += 256) {
        uint2 e = useL ? lc[i] : cb[i];
        U64 key = ((U64)e.x << 32) | (unsigned)(~e.y);
        if (key >= thr) {
            int p = atomicAdd(&scS, 1);
            if (p < 128) selS[p] = key;
        }
    }
    __syncthreads();
    int SC = scS; if (SC > 128) SC = 128;     // expected exactly 100
    if (tid < SC) {
        U64 my = selS[tid];
        int rank = 0;
        for (int j = 0; j < SC; j++) rank += (selS[j] > my) ? 1 : 0;
        if (rank < KSEL) topiS[rank] = (int)(~(unsigned)(my & 0xffffffffu));
    }
    __syncthreads();

    if (tid < KSEL) {
        int idx = topiS[tid];
        int qq = idx / HW, rr = idx - qq * HW;
        cx0S[tid] = (float)(qq % 60) / 60.0f;
        cy0S[tid] = (float)(qq / 60) / 60.0f;
        cx1S[tid] = (float)(rr % 60) / 60.0f;
        cy1S[tid] = (float)(rr / 60) / 60.0f;
    }
    __syncthreads();
    if (tid < 128) {
        const float* wr_ = W + tid * 200;
        float c0 = 0.f, c1 = 0.f, sx = 0.f, sy = 0.f;
        for (int k = 0; k < KSEL; k++) {
            float wx = wr_[2 * k], wy = wr_[2 * k + 1];
            c0 += cx0S[k] * wx + cy0S[k] * wy;
            c1 += cx1S[k] * wx + cy1S[k] * wy;
            sx += wx; sy += wy;
        }
        C0[batch * 128 + tid] = c0;
        C1[batch * 128 + tid] = c1;
        if (batch == 0) { Sx[tid] = sx; Sy[tid] = sy; }
    }
}

// ---- Pass F: out = x + affine emb (elementwise) ----------------------------
__global__ __launch_bounds__(256) void final_k(
    const float* __restrict__ x, const float* __restrict__ bias,
    const float* __restrict__ C0, const float* __restrict__ C1,
    const float* __restrict__ Sx, const float* __restrict__ Sy,
    float* __restrict__ out)
{
    int bd = blockIdx.x;
    int b = bd >> 7, d = bd & 127;
    float cst = bias[d] - ((b < 4) ? C0[b * 128 + d] : C1[(b - 4) * 128 + d]);
    float sx = Sx[d], sy = Sy[d];
    const float4* xin = (const float4*)(x + (size_t)bd * HW);
    float4* o4 = (float4*)(out + (size_t)bd * HW);
    for (int f = threadIdx.x; f < NF4; f += 256) {
        float4 v = xin[f];
        int p0 = f * 4;
        float gy = (float)(p0 / 60) / 60.0f;
        float gxb = (float)(p0 % 60);
        float add = cst + gy * sy;
        v.x += add + ((gxb       ) / 60.0f) * sx;
        v.y += add + ((gxb + 1.f) / 60.0f) * sx;
        v.z += add + ((gxb + 2.f) / 60.0f) * sx;
        v.w += add + ((gxb + 3.f) / 60.0f) * sx;
        o4[f] = v;
    }
}

extern "C" void kernel_launch(void* const* d_in, const int* in_sizes, int n_in,
                              void* d_out, int out_size, void* d_ws, size_t ws_size,
                              hipStream_t stream)
{
    const float* x    = (const float*)d_in[0];
    const float* W    = (const float*)d_in[1];
    const float* bias = (const float*)d_in[2];
    float* out = (float*)d_out;

    char* ws = (char*)d_ws;
    float*    den_row = (float*)(ws + 0);          // 57600
    float*    den_col = (float*)(ws + 57600);      // -> 115200
    U64*      rowmax  = (U64*)  (ws + 115200);     // -> 230400
    int*      cnt     = (int*)  (ws + 230400);     // 16
    float*    tau     = (float*)(ws + 230416);     // 16 -> 230432
    float*    lnDr    = (float*)(ws + 230464);     // -> 288064
    float*    lnDc    = (float*)(ws + 288064);     // -> 345664
    float*    minlnc  = (float*)(ws + 345664);     // 4*58*4 -> 346592
    int*      paircnt = (int*)  (ws + 346592);     // 4*58*4 -> 347520
    float*    C0      = (float*)(ws + 347584);     // -> 349632
    float*    C1      = (float*)(ws + 349632);     // -> 351680
    float*    Sx      = (float*)(ws + 351680);     // -> 352192
    float*    Sy      = (float*)(ws + 352192);     // -> 352704
    uint2*    cand    = (uint2*)(ws + 352768);     // 4*CAP*8 -> 4547072
    int*      pairrows= (int*)  (ws + 4547072);    // 4*58*3712*4 -> 7991808
    float*    maxvt   = (float*)(ws + 7991808);    // 4*58*3712*4 -> 11436544
    unsigned short* hiT = (unsigned short*)(ws + 11436544);  // 7602176 -> 19038720
    unsigned short* loT = (unsigned short*)(ws + 19038720);  // 7602176 -> 26640896

    hipMemsetAsync(ws, 0, 230432, stream);          // den/rowmax/cnt/tau
    hipMemsetAsync(ws + 346592, 0, 928, stream);    // paircnt

    conv_k       <<<dim3(58, 2, 8),    256, 0, stream>>>(x, hiT, loT);
    gemm_direct_k<<<dim3(29, 29, 4),   256, 0, stream>>>(hiT, loT, den_row, den_col, rowmax, maxvt);
    prep_k       <<<dim3(1, 1, 4),     256, 0, stream>>>(den_row, den_col, rowmax, lnDr, lnDc, minlnc, tau);
    pairs_k      <<<dim3(NT, 1, 4),    256, 0, stream>>>(maxvt, lnDr, minlnc, tau, pairrows, paircnt);
    recollect_k  <<<dim3(232, NT, 4),  256, 0, stream>>>(hiT, loT, lnDr, lnDc, tau, pairrows, paircnt, cand, cnt);
    select_k     <<<dim3(1, 1, 4),     256, 0, stream>>>(cand, cnt, W, C0, C1, Sx, Sy);
    final_k      <<<dim3(1024),        256, 0, stream>>>(x, bias, C0, C1, Sx, Sy, out);
}

// Round 5
// 266.432 us; speedup vs baseline: 1.3107x; 1.3107x over previous
//
#include <hip/hip_runtime.h>

#define HW 3600
#define PADR 3712            // 29*128 padded rows
#define NF4 900
#define CAP 16384
#define KSEL 100
#define NT 58                // 64-col tiles
typedef unsigned long long U64;

using short8   = __attribute__((ext_vector_type(8))) short;
using float4v  = __attribute__((ext_vector_type(4))) float;
using float16v = __attribute__((ext_vector_type(16))) float;

__device__ __forceinline__ unsigned monof(float f) {
    unsigned b = __float_as_uint(f);
    return (b & 0x80000000u) ? ~b : (b | 0x80000000u);
}
__device__ __forceinline__ float unmonof(unsigned m) {
    return __uint_as_float((m & 0x80000000u) ? (m ^ 0x80000000u) : ~m);
}
__device__ __forceinline__ unsigned short f2bf(float f) {   // RNE
    unsigned b = __float_as_uint(f);
    return (unsigned short)((b + 0x7FFFu + ((b >> 16) & 1u)) >> 16);
}
__device__ __forceinline__ float bf2f(unsigned short h) {
    return __uint_as_float(((unsigned)h) << 16);
}
__device__ __forceinline__ void async16(const void* g, void* l) {
    __builtin_amdgcn_global_load_lds((const __attribute__((address_space(1))) void*)g,
                                     (__attribute__((address_space(3))) void*)l, 16, 0, 0);
}

// chunk-major element address (in shorts): buf[b][rblk][kb][row128][8]
// addr = ((b*29 + (row>>7))*16 + (k>>3))*1024 + (row&127)*8 + (k&7)

// ---- Pass 0: convert x (b,d,l) -> chunk-major split-bf16 hiT/loT -----------
__global__ __launch_bounds__(256) void conv_k(
    const float* __restrict__ x,
    unsigned short* __restrict__ hiT, unsigned short* __restrict__ loT)
{
    int b = blockIdx.z, l0 = blockIdx.x * 64, d0 = blockIdx.y * 64;
    __shared__ float t[64][65];
    int tid = threadIdx.x;
#pragma unroll
    for (int r = 0; r < 4; r++) {
        int idx = tid + 256 * r;              // 1024 float4 slots
        int d = idx >> 4, lq = idx & 15;
        int l = l0 + lq * 4;
        const float* src = x + ((size_t)b * 128 + d0 + d) * HW;
        float4 v;
        if (l + 3 < HW) v = *(const float4*)(src + l);
        else {
            v.x = (l     < HW) ? src[l]     : 0.f;
            v.y = (l + 1 < HW) ? src[l + 1] : 0.f;
            v.z = (l + 2 < HW) ? src[l + 2] : 0.f;
            v.w = (l + 3 < HW) ? src[l + 3] : 0.f;
        }
        t[lq * 4 + 0][d] = v.x; t[lq * 4 + 1][d] = v.y;
        t[lq * 4 + 2][d] = v.z; t[lq * 4 + 3][d] = v.w;
    }
    __syncthreads();
    const int rblk = l0 >> 7;                 // l0 multiple of 64 -> same for all l<64
#pragma unroll
    for (int r = 0; r < 2; r++) {
        int idx = tid + 256 * r;              // 512 chunks of 8 bf16
        int l = idx >> 3, dq = idx & 7;
        unsigned hp[4], lp[4];
#pragma unroll
        for (int j = 0; j < 4; j++) {
            float f0 = t[l][dq * 8 + 2 * j], f1 = t[l][dq * 8 + 2 * j + 1];
            unsigned short h0 = f2bf(f0), h1 = f2bf(f1);
            unsigned short g0 = f2bf(f0 - bf2f(h0)), g1 = f2bf(f1 - bf2f(h1));
            hp[j] = (unsigned)h0 | ((unsigned)h1 << 16);
            lp[j] = (unsigned)g0 | ((unsigned)g1 << 16);
        }
        size_t o = ((size_t)(b * 29 + rblk) * 16 + (d0 >> 3) + dq) * 1024
                 + (size_t)((l0 + l) & 127) * 8;
        *(uint4*)(hiT + o) = make_uint4(hp[0], hp[1], hp[2], hp[3]);
        *(uint4*)(loT + o) = make_uint4(lp[0], lp[1], lp[2], lp[3]);
    }
}

// ---- Pass A: LDS-staged (global_load_lds) 32x32x16 split-bf16 GEMM ---------
// -> den_row, den_col, rowmax, per-(row,64coltile) maxv. No sm stores.
__global__ __launch_bounds__(256) void gemm_mfma_k(
    const unsigned short* __restrict__ hiT, const unsigned short* __restrict__ loT,
    float* __restrict__ den_row, float* __restrict__ den_col,
    U64* __restrict__ rowmax, float* __restrict__ maxvt)
{
    const int batch = blockIdx.z, bx = blockIdx.x, by = blockIdx.y;
    __shared__ __align__(16) unsigned short stage[4][4][128][8];  // part,kb,row,8
    __shared__ float rowsumS[128], colsumS[128];
    __shared__ U64 rowmaxS[128];

    const int tid = threadIdx.x;
    const int lane = tid & 63, w = tid >> 6;
    const int wr = w >> 1, wc = w & 1;
    const int l31 = lane & 31, h = lane >> 5;

    if (tid < 128) { rowsumS[tid] = 0.f; colsumS[tid] = 0.f; rowmaxS[tid] = 0ull; }

    // per-wave staging source: wave w stages part w (Ah,Al,Bh,Bl)
    const unsigned short* psrc = (w == 0) ? hiT : (w == 1) ? loT : (w == 2) ? hiT : loT;
    const int bsel = (w < 2) ? batch : batch + 4;
    const int rblk = (w < 2) ? by : bx;
    const size_t cbase = ((size_t)(bsel * 29 + rblk) * 16) * 1024;

    float16v acc[2][2];
#pragma unroll
    for (int i = 0; i < 2; i++)
#pragma unroll
        for (int j = 0; j < 2; j++) acc[i][j] = (float16v)(0.f);

    for (int k0 = 0; k0 < 128; k0 += 32) {
#pragma unroll
        for (int i = 0; i < 8; i++) {
            int kb = i >> 1, half = i & 1;
            const unsigned short* g = psrc + cbase + (size_t)((k0 >> 3) + kb) * 1024
                                    + (half << 9) + lane * 8;
            async16(g, &stage[w][kb][half << 6][0]);
        }
        __syncthreads();
#pragma unroll
        for (int j = 0; j < 2; j++) {
            int kb = j * 2 + h;
            short8 ah[2], al[2], bh[2], bl[2];
#pragma unroll
            for (int t = 0; t < 2; t++) {
                ah[t] = *(const short8*)&stage[0][kb][wr * 64 + t * 32 + l31][0];
                al[t] = *(const short8*)&stage[1][kb][wr * 64 + t * 32 + l31][0];
                bh[t] = *(const short8*)&stage[2][kb][wc * 64 + t * 32 + l31][0];
                bl[t] = *(const short8*)&stage[3][kb][wc * 64 + t * 32 + l31][0];
            }
#pragma unroll
            for (int mt = 0; mt < 2; mt++)
#pragma unroll
                for (int nt = 0; nt < 2; nt++) {
                    acc[mt][nt] = __builtin_amdgcn_mfma_f32_32x32x16_bf16(ah[mt], bh[nt], acc[mt][nt], 0, 0, 0);
                    acc[mt][nt] = __builtin_amdgcn_mfma_f32_32x32x16_bf16(ah[mt], bl[nt], acc[mt][nt], 0, 0, 0);
                    acc[mt][nt] = __builtin_amdgcn_mfma_f32_32x32x16_bf16(al[mt], bh[nt], acc[mt][nt], 0, 0, 0);
                }
        }
        __syncthreads();
    }

    // ---- epilogue: C/D layout col=lane&31, row=(reg&3)+8*(reg>>2)+4*(lane>>5)
    const float scale = 0.078125f;    // 1/(128*0.1)
    float cs[2] = {0.f, 0.f};
    const int ct = bx * 2 + wc;
#pragma unroll
    for (int mt = 0; mt < 2; mt++) {
#pragma unroll
        for (int reg = 0; reg < 16; reg++) {
            int rloc = (reg & 3) + 8 * (reg >> 2) + 4 * h;
            int row128 = wr * 64 + mt * 32 + rloc;
            int l = by * 128 + row128;
            bool lv = (l < HW);
            float rs = 0.f; U64 pk = 0ull;
#pragma unroll
            for (int nt = 0; nt < 2; nt++) {
                int s = bx * 128 + wc * 64 + nt * 32 + l31;
                float v = acc[mt][nt][reg] * scale;
                if (s < HW) {
                    float e = __expf(v);
                    rs += e;
                    if (lv) cs[nt] += e;
                    U64 k = ((U64)monof(v) << 32) | (unsigned)s;
                    if (k > pk) pk = k;
                }
            }
#pragma unroll
            for (int off = 1; off < 32; off <<= 1) {
                rs += __shfl_xor(rs, off);
                U64 o = __shfl_xor(pk, off);
                if (o > pk) pk = o;
            }
            if (l31 == 0) {
                atomicAdd(&rowsumS[row128], rs);
                atomicMax(&rowmaxS[row128], pk);
                if (lv) maxvt[((size_t)batch * NT + ct) * PADR + l] =
                            unmonof((unsigned)(pk >> 32));
            }
        }
    }
#pragma unroll
    for (int nt = 0; nt < 2; nt++) {
        cs[nt] += __shfl_xor(cs[nt], 32);
        if (h == 0) atomicAdd(&colsumS[wc * 64 + nt * 32 + l31], cs[nt]);
    }
    __syncthreads();
    if (tid < 128) {
        int l = by * 128 + tid;
        if (l < HW) {
            atomicAdd(&den_row[(size_t)batch * HW + l], rowsumS[tid]);
            atomicMax(&rowmax[(size_t)batch * HW + l], rowmaxS[tid]);
        }
        int s = bx * 128 + tid;
        if (s < HW) atomicAdd(&den_col[(size_t)batch * HW + s], colsumS[tid]);
    }
}

// ---- Pass B: logs, minlnc/tile, exact tau via 4096-bin hist + rank ---------
__global__ __launch_bounds__(256) void prep_k(
    const float* __restrict__ den_row, const float* __restrict__ den_col,
    const U64* __restrict__ rowmax,
    float* __restrict__ lnDr, float* __restrict__ lnDc,
    float* __restrict__ minlnc, float* __restrict__ tau)
{
    const int batch = blockIdx.z;
    const int tid = threadIdx.x;
    __shared__ float ldrS[HW];
    __shared__ float lncS[HW];
    __shared__ unsigned keyS[HW];
    __shared__ unsigned hist[4096];
    __shared__ unsigned pc[256];
    __shared__ U64 list[HW];
    __shared__ int cntS, binS;
    __shared__ float tauS;

    for (int i = tid; i < HW; i += 256) {
        float ldr = __logf(den_row[(size_t)batch * HW + i]);
        float ldc = __logf(den_col[(size_t)batch * HW + i]);
        lnDr[(size_t)batch * HW + i] = ldr;
        lnDc[(size_t)batch * HW + i] = ldc;
        ldrS[i] = ldr; lncS[i] = ldc;
    }
    for (int i = tid; i < 4096; i += 256) hist[i] = 0u;
    if (tid == 0) cntS = 0;
    __syncthreads();

    if (tid < NT) {
        float mn = 3.4e38f;
        int s0 = tid * 64, s1 = s0 + 64; if (s1 > HW) s1 = HW;
        for (int s = s0; s < s1; s++) mn = fminf(mn, lncS[s]);
        minlnc[batch * NT + tid] = mn;
    }
    for (int i = tid; i < HW; i += 256) {
        U64 rm = rowmax[(size_t)batch * HW + i];
        float mv = unmonof((unsigned)(rm >> 32));
        unsigned col = (unsigned)(rm & 0xffffffffu);
        unsigned km = monof(2.0f * mv - ldrS[i] - lncS[col]);
        keyS[i] = km;
        atomicAdd(&hist[km >> 20], 1u);
    }
    __syncthreads();
    {   // partial sums of 16-bin chunks
        unsigned s = 0;
        for (int j = 0; j < 16; j++) s += hist[tid * 16 + j];
        pc[tid] = s;
    }
    __syncthreads();
    if (tid == 0) {
        unsigned cum = 0; int cs_ = 255;
        for (; cs_ >= 0; cs_--) {
            if (cum + pc[cs_] >= (unsigned)KSEL) break;
            cum += pc[cs_];
        }
        int b = cs_ * 16 + 15;
        for (; b >= cs_ * 16; b--) { cum += hist[b]; if (cum >= (unsigned)KSEL) break; }
        if (b < cs_ * 16) b = cs_ * 16;
        binS = b;
    }
    __syncthreads();
    unsigned bstar = (unsigned)binS;
    for (int i = tid; i < HW; i += 256)
        if ((keyS[i] >> 20) >= bstar) {
            int p = atomicAdd(&cntS, 1);
            list[p] = ((U64)keyS[i] << 32) | (unsigned)(HW - i);  // unique keys
        }
    __syncthreads();
    int Mr = cntS;
    for (int i = tid; i < Mr; i += 256) {
        U64 e = list[i];
        int r = 0;
        for (int j = 0; j < Mr; j++) r += (list[j] > e) ? 1 : 0;
        if (r == KSEL - 1) tauS = unmonof((unsigned)(e >> 32));
    }
    __syncthreads();
    if (tid == 0) tau[batch] = tauS - 1e-4f;
}

// ---- Pass C: build (row, 64-col-tile) pair lists from maxvt bound ----------
__global__ __launch_bounds__(256) void pairs_k(
    const float* __restrict__ maxvt, const float* __restrict__ lnDr,
    const float* __restrict__ minlnc, const float* __restrict__ tau,
    int* __restrict__ pairrows, int* __restrict__ paircnt)
{
    const int batch = blockIdx.z, t = blockIdx.x;
    const float tv = tau[batch] - 1e-4f;
    const float ml = minlnc[batch * NT + t];
    const float* mv = maxvt + ((size_t)batch * NT + t) * PADR;
    const float* ldr = lnDr + (size_t)batch * HW;
    int* pr = pairrows + ((size_t)batch * NT + t) * PADR;
    for (int r = threadIdx.x; r < HW; r += 256) {
        float b = 2.0f * mv[r] - ldr[r] - ml;   // NaN -> false -> skip
        if (b >= tv) {
            int p = atomicAdd(&paircnt[batch * NT + t], 1);
            pr[p] = r;
        }
    }
}

// ---- Pass D: recompute surviving pairs (16x16x32 chain), collect -----------
__global__ __launch_bounds__(256) void recollect_k(
    const unsigned short* __restrict__ hiT, const unsigned short* __restrict__ loT,
    const float* __restrict__ lnDr, const float* __restrict__ lnDc,
    const float* __restrict__ tau, const int* __restrict__ pairrows,
    const int* __restrict__ paircnt, uint2* __restrict__ cand,
    int* __restrict__ cnt)
{
    const int t = blockIdx.x, batch = blockIdx.y;
    const int pc = paircnt[batch * NT + t];
    if (pc == 0) return;
    const float tv = tau[batch];
    const int* pr = pairrows + ((size_t)batch * NT + t) * PADR;

    const unsigned short* Ah = hiT + (size_t)batch * PADR * 128;
    const unsigned short* Al = loT + (size_t)batch * PADR * 128;
    const unsigned short* Bh = hiT + (size_t)(batch + 4) * PADR * 128;
    const unsigned short* Bl = loT + (size_t)(batch + 4) * PADR * 128;

    const int tid = threadIdx.x;
    const int lane = tid & 63, w = tid >> 6;
    const int m = lane & 15, q = lane >> 4;
    const float scale = 0.078125f;

    for (int g = w; g * 16 < pc; g += 4) {
        int pi = g * 16 + m;
        int rowv = (pi < pc) ? pr[pi] : HW;          // pad row: zeros
        float ldrv = (pi < pc) ? lnDr[(size_t)batch * HW + rowv] : 0.f;
        size_t arow = ((size_t)(rowv >> 7) * 16) * 1024 + (size_t)(rowv & 127) * 8;

        float4v acc[4];
#pragma unroll
        for (int i = 0; i < 4; i++) acc[i] = (float4v){0.f, 0.f, 0.f, 0.f};
#pragma unroll
        for (int k0 = 0; k0 < 128; k0 += 32) {
            int kb = (k0 >> 3) + q;
            short8 ah = *(const short8*)(Ah + arow + (size_t)kb * 1024);
            short8 al = *(const short8*)(Al + arow + (size_t)kb * 1024);
#pragma unroll
            for (int nt = 0; nt < 4; nt++) {
                int c = t * 64 + nt * 16 + m;        // < PADR
                size_t brow = ((size_t)(c >> 7) * 16 + kb) * 1024 + (size_t)(c & 127) * 8;
                short8 bh = *(const short8*)(Bh + brow);
                short8 bl = *(const short8*)(Bl + brow);
                acc[nt] = __builtin_amdgcn_mfma_f32_16x16x32_bf16(ah, bh, acc[nt], 0, 0, 0);
                acc[nt] = __builtin_amdgcn_mfma_f32_16x16x32_bf16(ah, bl, acc[nt], 0, 0, 0);
                acc[nt] = __builtin_amdgcn_mfma_f32_16x16x32_bf16(al, bh, acc[nt], 0, 0, 0);
            }
        }
#pragma unroll
        for (int nt = 0; nt < 4; nt++) {
            int c = t * 64 + nt * 16 + m;
            if (c >= HW) continue;
            float ldc = lnDc[(size_t)batch * HW + c];
#pragma unroll
            for (int r = 0; r < 4; r++) {
                int ri = q * 4 + r;                  // output row = C/D row
                if (g * 16 + ri >= pc) continue;
                int rowo = __shfl(rowv, ri);
                float ldro = __shfl(ldrv, ri);
                float v = acc[nt][r] * scale;
                float tt = 2.0f * v - ldro - ldc;
                if (tt >= tv) {
                    int p = atomicAdd(&cnt[batch], 1);
                    if (p < CAP)
                        cand[(size_t)batch * CAP + p] =
                            make_uint2(monof(tt), (unsigned)(rowo * HW + c));
                }
            }
        }
    }
}

// ---- Pass E: exact ordered top-100 via M^2 rank, fold coords into W --------
__global__ __launch_bounds__(256) void select_k(
    const uint2* __restrict__ cand, const int* __restrict__ cnt,
    const float* __restrict__ W,
    float* __restrict__ C0, float* __restrict__ C1,
    float* __restrict__ Sx, float* __restrict__ Sy)
{
    const int batch = blockIdx.z;
    const int tid = threadIdx.x;
    const uint2* cb = cand + (size_t)batch * CAP;
    int M = cnt[batch]; if (M > CAP) M = CAP;

    __shared__ U64 lk[6144];
    __shared__ int topiS[KSEL];
    __shared__ float cx0S[KSEL], cy0S[KSEL], cx1S[KSEL], cy1S[KSEL];

    const bool useL = (M <= 6144);
    if (useL)
        for (int i = tid; i < M; i += 256) {
            uint2 e = cb[i];
            lk[i] = ((U64)e.x << 32) | (unsigned)(~e.y);
        }
    __syncthreads();

    for (int i = tid; i < M; i += 256) {
        U64 e;
        if (useL) e = lk[i];
        else { uint2 t = cb[i]; e = ((U64)t.x << 32) | (unsigned)(~t.y); }
        int r = 0;
        for (int j = 0; j < M; j++) {
            U64 o;
            if (useL) o = lk[j];
            else { uint2 t = cb[j]; o = ((U64)t.x << 32) | (unsigned)(~t.y); }
            r += (o > e) ? 1 : 0;
        }
        if (r < KSEL) topiS[r] = (int)(~(unsigned)(e & 0xffffffffu));
    }
    __syncthreads();

    if (tid < KSEL) {
        int idx = topiS[tid];
        int qq = idx / HW, rr = idx - qq * HW;
        cx0S[tid] = (float)(qq % 60) / 60.0f;
        cy0S[tid] = (float)(qq / 60) / 60.0f;
        cx1S[tid] = (float)(rr % 60) / 60.0f;
        cy1S[tid] = (float)(rr / 60) / 60.0f;
    }
    __syncthreads();
    if (tid < 128) {
        const float* wr_ = W + tid * 200;
        float c0 = 0.f, c1 = 0.f, sx = 0.f, sy = 0.f;
        for (int k = 0; k < KSEL; k++) {
            float wx = wr_[2 * k], wy = wr_[2 * k + 1];
            c0 += cx0S[k] * wx + cy0S[k] * wy;
            c1 += cx1S[k] * wx + cy1S[k] * wy;
            sx += wx; sy += wy;
        }
        C0[batch * 128 + tid] = c0;
        C1[batch * 128 + tid] = c1;
        if (batch == 0) { Sx[tid] = sx; Sy[tid] = sy; }
    }
}

// ---- Pass F: out = x + affine emb (elementwise) ----------------------------
__global__ __launch_bounds__(256) void final_k(
    const float* __restrict__ x, const float* __restrict__ bias,
    const float* __restrict__ C0, const float* __restrict__ C1,
    const float* __restrict__ Sx, const float* __restrict__ Sy,
    float* __restrict__ out)
{
    int bd = blockIdx.x;
    int b = bd >> 7, d = bd & 127;
    float cst = bias[d] - ((b < 4) ? C0[b * 128 + d] : C1[(b - 4) * 128 + d]);
    float sx = Sx[d], sy = Sy[d];
    const float4* xin = (const float4*)(x + (size_t)bd * HW);
    float4* o4 = (float4*)(out + (size_t)bd * HW);
    for (int f = threadIdx.x; f < NF4; f += 256) {
        float4 v = xin[f];
        int p0 = f * 4;
        float gy = (float)(p0 / 60) / 60.0f;
        float gxb = (float)(p0 % 60);
        float add = cst + gy * sy;
        v.x += add + ((gxb       ) / 60.0f) * sx;
        v.y += add + ((gxb + 1.f) / 60.0f) * sx;
        v.z += add + ((gxb + 2.f) / 60.0f) * sx;
        v.w += add + ((gxb + 3.f) / 60.0f) * sx;
        o4[f] = v;
    }
}

extern "C" void kernel_launch(void* const* d_in, const int* in_sizes, int n_in,
                              void* d_out, int out_size, void* d_ws, size_t ws_size,
                              hipStream_t stream)
{
    const float* x    = (const float*)d_in[0];
    const float* W    = (const float*)d_in[1];
    const float* bias = (const float*)d_in[2];
    float* out = (float*)d_out;

    char* ws = (char*)d_ws;
    float*    den_row = (float*)(ws + 0);          // 57600
    float*    den_col = (float*)(ws + 57600);      // -> 115200
    U64*      rowmax  = (U64*)  (ws + 115200);     // -> 230400
    int*      cnt     = (int*)  (ws + 230400);     // 16
    float*    tau     = (float*)(ws + 230416);     // -> 230432
    float*    lnDr    = (float*)(ws + 230464);     // -> 288064
    float*    lnDc    = (float*)(ws + 288064);     // -> 345664
    float*    minlnc  = (float*)(ws + 345664);     // -> 346592
    int*      paircnt = (int*)  (ws + 346592);     // -> 347520
    float*    C0      = (float*)(ws + 347584);     // -> 349632
    float*    C1      = (float*)(ws + 349632);     // -> 351680
    float*    Sx      = (float*)(ws + 351680);     // -> 352192
    float*    Sy      = (float*)(ws + 352192);     // -> 352704
    uint2*    cand    = (uint2*)(ws + 352768);     // 4*16384*8 -> 877056
    int*      pairrows= (int*)  (ws + 877056);     // 3444736 -> 4321792
    float*    maxvt   = (float*)(ws + 4321792);    // 3444736 -> 7766528
    unsigned short* hiT = (unsigned short*)(ws + 7766528);   // 7602176 -> 15368704
    unsigned short* loT = (unsigned short*)(ws + 15368704);  // 7602176 -> 22970880

    hipMemsetAsync(ws, 0, 230432, stream);          // den/rowmax/cnt/tau
    hipMemsetAsync(ws + 346592, 0, 928, stream);    // paircnt

    conv_k     <<<dim3(58, 2, 8),  256, 0, stream>>>(x, hiT, loT);
    gemm_mfma_k<<<dim3(29, 29, 4), 256, 0, stream>>>(hiT, loT, den_row, den_col, rowmax, maxvt);
    prep_k     <<<dim3(1, 1, 4),   256, 0, stream>>>(den_row, den_col, rowmax, lnDr, lnDc, minlnc, tau);
    pairs_k    <<<dim3(NT, 1, 4),  256, 0, stream>>>(maxvt, lnDr, minlnc, tau, pairrows, paircnt);
    recollect_k<<<dim3(NT, 4),     256, 0, stream>>>(hiT, loT, lnDr, lnDc, tau, pairrows, paircnt, cand, cnt);
    select_k   <<<dim3(1, 1, 4),   256, 0, stream>>>(cand, cnt, W, C0, C1, Sx, Sy);
    final_k    <<<dim3(1024),      256, 0, stream>>>(x, bias, C0, C1, Sx, Sy, out);
}

// Round 6
// 263.011 us; speedup vs baseline: 1.3278x; 1.0130x over previous
//
#include <hip/hip_runtime.h>

#define HW 3600
#define PADR 3712            // 29*128 padded rows
#define NF4 900
#define CAP 16384
#define KSEL 100
#define NT 58                // 64-col tiles
typedef unsigned long long U64;

using short8   = __attribute__((ext_vector_type(8))) short;
using float4v  = __attribute__((ext_vector_type(4))) float;
using float16v = __attribute__((ext_vector_type(16))) float;

__device__ __forceinline__ unsigned monof(float f) {
    unsigned b = __float_as_uint(f);
    return (b & 0x80000000u) ? ~b : (b | 0x80000000u);
}
__device__ __forceinline__ float unmonof(unsigned m) {
    return __uint_as_float((m & 0x80000000u) ? (m ^ 0x80000000u) : ~m);
}
__device__ __forceinline__ unsigned short f2bf(float f) {   // RNE
    unsigned b = __float_as_uint(f);
    return (unsigned short)((b + 0x7FFFu + ((b >> 16) & 1u)) >> 16);
}
__device__ __forceinline__ float bf2f(unsigned short h) {
    return __uint_as_float(((unsigned)h) << 16);
}
__device__ __forceinline__ void async16(const void* g, void* l) {
    __builtin_amdgcn_global_load_lds((const __attribute__((address_space(1))) void*)g,
                                     (__attribute__((address_space(3))) void*)l, 16, 0, 0);
}

// chunk-major element address (in shorts): buf[b][rblk][kb][row128][8]

// ---- Pass 0: convert x (b,d,l) -> chunk-major split-bf16 hiT/loT -----------
__global__ __launch_bounds__(256) void conv_k(
    const float* __restrict__ x,
    unsigned short* __restrict__ hiT, unsigned short* __restrict__ loT)
{
    int b = blockIdx.z, l0 = blockIdx.x * 64, d0 = blockIdx.y * 64;
    __shared__ float t[64][65];
    int tid = threadIdx.x;
#pragma unroll
    for (int r = 0; r < 4; r++) {
        int idx = tid + 256 * r;              // 1024 float4 slots
        int d = idx >> 4, lq = idx & 15;
        int l = l0 + lq * 4;
        const float* src = x + ((size_t)b * 128 + d0 + d) * HW;
        float4 v;
        if (l + 3 < HW) v = *(const float4*)(src + l);
        else {
            v.x = (l     < HW) ? src[l]     : 0.f;
            v.y = (l + 1 < HW) ? src[l + 1] : 0.f;
            v.z = (l + 2 < HW) ? src[l + 2] : 0.f;
            v.w = (l + 3 < HW) ? src[l + 3] : 0.f;
        }
        t[lq * 4 + 0][d] = v.x; t[lq * 4 + 1][d] = v.y;
        t[lq * 4 + 2][d] = v.z; t[lq * 4 + 3][d] = v.w;
    }
    __syncthreads();
    const int rblk = l0 >> 7;
#pragma unroll
    for (int r = 0; r < 2; r++) {
        int idx = tid + 256 * r;              // 512 chunks of 8 bf16
        int l = idx & 63, dq = idx >> 6;      // row-inner -> coalesced stores
        unsigned hp[4], lp[4];
#pragma unroll
        for (int j = 0; j < 4; j++) {
            float f0 = t[l][dq * 8 + 2 * j], f1 = t[l][dq * 8 + 2 * j + 1];
            unsigned short h0 = f2bf(f0), h1 = f2bf(f1);
            unsigned short g0 = f2bf(f0 - bf2f(h0)), g1 = f2bf(f1 - bf2f(h1));
            hp[j] = (unsigned)h0 | ((unsigned)h1 << 16);
            lp[j] = (unsigned)g0 | ((unsigned)g1 << 16);
        }
        size_t o = ((size_t)(b * 29 + rblk) * 16 + (d0 >> 3) + dq) * 1024
                 + (size_t)((l0 + l) & 127) * 8;
        *(uint4*)(hiT + o) = make_uint4(hp[0], hp[1], hp[2], hp[3]);
        *(uint4*)(loT + o) = make_uint4(lp[0], lp[1], lp[2], lp[3]);
    }
}

// ---- Pass A: LDS-staged 32x32x16 split-bf16 GEMM; f32-only stats epilogue --
__global__ __launch_bounds__(256) void gemm_mfma_k(
    const unsigned short* __restrict__ hiT, const unsigned short* __restrict__ loT,
    float* __restrict__ den_row, float* __restrict__ den_col,
    float* __restrict__ maxvt)
{
    const int batch = blockIdx.z, bx = blockIdx.x, by = blockIdx.y;
    __shared__ __align__(16) unsigned short stage[4][4][128][8];  // part,kb,row,8
    __shared__ float rowsumS[128], colsumS[128];

    const int tid = threadIdx.x;
    const int lane = tid & 63, w = tid >> 6;
    const int wr = w >> 1, wc = w & 1;
    const int l31 = lane & 31, h = lane >> 5;

    if (tid < 128) { rowsumS[tid] = 0.f; colsumS[tid] = 0.f; }

    const unsigned short* psrc = (w == 0) ? hiT : (w == 1) ? loT : (w == 2) ? hiT : loT;
    const int bsel = (w < 2) ? batch : batch + 4;
    const int rblk = (w < 2) ? by : bx;
    const size_t cbase = ((size_t)(bsel * 29 + rblk) * 16) * 1024;

    float16v acc[2][2];
#pragma unroll
    for (int i = 0; i < 2; i++)
#pragma unroll
        for (int j = 0; j < 2; j++) acc[i][j] = (float16v)(0.f);

    for (int k0 = 0; k0 < 128; k0 += 32) {
#pragma unroll
        for (int i = 0; i < 8; i++) {
            int kb = i >> 1, half = i & 1;
            const unsigned short* g = psrc + cbase + (size_t)((k0 >> 3) + kb) * 1024
                                    + (half << 9) + lane * 8;
            async16(g, &stage[w][kb][half << 6][0]);
        }
        __syncthreads();
#pragma unroll
        for (int j = 0; j < 2; j++) {
            int kb = j * 2 + h;
            short8 ah[2], al[2], bh[2], bl[2];
#pragma unroll
            for (int t = 0; t < 2; t++) {
                ah[t] = *(const short8*)&stage[0][kb][wr * 64 + t * 32 + l31][0];
                al[t] = *(const short8*)&stage[1][kb][wr * 64 + t * 32 + l31][0];
                bh[t] = *(const short8*)&stage[2][kb][wc * 64 + t * 32 + l31][0];
                bl[t] = *(const short8*)&stage[3][kb][wc * 64 + t * 32 + l31][0];
            }
#pragma unroll
            for (int mt = 0; mt < 2; mt++)
#pragma unroll
                for (int nt = 0; nt < 2; nt++) {
                    acc[mt][nt] = __builtin_amdgcn_mfma_f32_32x32x16_bf16(ah[mt], bh[nt], acc[mt][nt], 0, 0, 0);
                    acc[mt][nt] = __builtin_amdgcn_mfma_f32_32x32x16_bf16(ah[mt], bl[nt], acc[mt][nt], 0, 0, 0);
                    acc[mt][nt] = __builtin_amdgcn_mfma_f32_32x32x16_bf16(al[mt], bh[nt], acc[mt][nt], 0, 0, 0);
                }
        }
        __syncthreads();
    }

    // ---- epilogue (f32 only): rowsum, colsum, per-(row,64tile) max ----
    const float scale = 0.078125f;   // 1/(128*0.1)
    float cs[2] = {0.f, 0.f};
    const int ct = bx * 2 + wc;
#pragma unroll
    for (int mt = 0; mt < 2; mt++) {
#pragma unroll
        for (int reg = 0; reg < 16; reg++) {
            int rloc = (reg & 3) + 8 * (reg >> 2) + 4 * h;
            int row128 = wr * 64 + mt * 32 + rloc;
            int l = by * 128 + row128;
            bool lv = (l < HW);
            float rs = 0.f, mx = -3.4e38f;
#pragma unroll
            for (int nt = 0; nt < 2; nt++) {
                int s = bx * 128 + wc * 64 + nt * 32 + l31;
                float v = acc[mt][nt][reg] * scale;
                if (s < HW) {
                    float e = __expf(v);
                    rs += e;
                    if (lv) cs[nt] += e;
                    mx = fmaxf(mx, v);
                }
            }
#pragma unroll
            for (int off = 1; off < 32; off <<= 1) {
                rs += __shfl_xor(rs, off);
                mx = fmaxf(mx, __shfl_xor(mx, off));
            }
            if (l31 == 0) {
                atomicAdd(&rowsumS[row128], rs);
                if (lv) maxvt[((size_t)batch * NT + ct) * PADR + l] = mx;
            }
        }
    }
#pragma unroll
    for (int nt = 0; nt < 2; nt++) {
        cs[nt] += __shfl_xor(cs[nt], 32);
        if (h == 0) atomicAdd(&colsumS[wc * 64 + nt * 32 + l31], cs[nt]);
    }
    __syncthreads();
    if (tid < 128) {
        int l = by * 128 + tid;
        if (l < HW) atomicAdd(&den_row[(size_t)batch * HW + l], rowsumS[tid]);
        int s = bx * 128 + tid;
        if (s < HW) atomicAdd(&den_col[(size_t)batch * HW + s], colsumS[tid]);
    }
}

// ---- Pass B1: ln of all denominators (flat, parallel) ----------------------
__global__ __launch_bounds__(256) void logs_k(
    const float* __restrict__ den, float* __restrict__ lnD)
{
    int i = blockIdx.x * 256 + threadIdx.x;
    if (i < 28800) lnD[i] = __logf(den[i]);
}

// ---- Pass B2: per-(batch,64tile) min/max of lnDc ---------------------------
__global__ __launch_bounds__(64) void tilestat_k(
    const float* __restrict__ lnDc, float* __restrict__ minlnc, float* __restrict__ maxlnc)
{
    int t = blockIdx.x, b = blockIdx.z, tid = threadIdx.x;
    int j = t * 64 + tid;
    float v = (j < HW) ? lnDc[(size_t)b * HW + j] : 0.f;
    float mn = (j < HW) ? v : 3.4e38f;
    float mx = (j < HW) ? v : -3.4e38f;
#pragma unroll
    for (int off = 1; off < 64; off <<= 1) {
        mn = fminf(mn, __shfl_xor(mn, off));
        mx = fmaxf(mx, __shfl_xor(mx, off));
    }
    if (tid == 0) {
        if (mx == -3.4e38f) { mx = 1e30f; mn = 1e30f; }   // empty tile
        minlnc[b * NT + t] = mn;
        maxlnc[b * NT + t] = mx;
    }
}

// ---- Pass B3: per-row champion-key lower bound -----------------------------
// key_lb[j] = max_t (2*maxvt[t][j] - maxlnc[t]) - lnDr[j]  <= true row champion key
__global__ __launch_bounds__(256) void keylb_k(
    const float* __restrict__ maxvt, const float* __restrict__ lnDr,
    const float* __restrict__ maxlnc, float* __restrict__ keylb)
{
    int b = blockIdx.z, j = blockIdx.x * 256 + threadIdx.x;
    __shared__ float mls[NT];
    if (threadIdx.x < NT) mls[threadIdx.x] = maxlnc[b * NT + threadIdx.x];
    __syncthreads();
    if (j >= HW) return;
    float best = -3.4e38f;
#pragma unroll 2
    for (int t = 0; t < NT; t++) {
        float v = maxvt[((size_t)b * NT + t) * PADR + j];
        best = fmaxf(best, 2.0f * v - mls[t]);
    }
    keylb[(size_t)b * HW + j] = best - lnDr[(size_t)b * HW + j];
}

// ---- Pass B4: exact 100th-largest key_lb via 2-level hist + rank -> tau ----
__global__ __launch_bounds__(256) void tau_k(
    const float* __restrict__ keylb, float* __restrict__ tau)
{
    const int b = blockIdx.z, tid = threadIdx.x;
    __shared__ unsigned keyS[HW];
    __shared__ unsigned hist[4096];
    __shared__ unsigned pc[256];
    __shared__ int b1S, c1S, b2S, lcnt;
    __shared__ unsigned bestS;
    __shared__ unsigned list[1024];

    for (int i = tid; i < 4096; i += 256) hist[i] = 0u;
    if (tid == 0) { lcnt = 0; bestS = 0u; }
    __syncthreads();
    for (int i = tid; i < HW; i += 256) {
        unsigned k = monof(keylb[(size_t)b * HW + i]);
        keyS[i] = k;
        atomicAdd(&hist[k >> 20], 1u);
    }
    __syncthreads();
    { unsigned s = 0; for (int j = 0; j < 16; j++) s += hist[tid * 16 + j]; pc[tid] = s; }
    __syncthreads();
    if (tid == 0) {
        unsigned cum = 0; int cs_ = 255;
        for (; cs_ > 0; cs_--) { if (cum + pc[cs_] >= (unsigned)KSEL) break; cum += pc[cs_]; }
        int bb = cs_ * 16 + 15;
        for (; bb > cs_ * 16; bb--) { if (cum + hist[bb] >= (unsigned)KSEL) break; cum += hist[bb]; }
        b1S = bb; c1S = (int)cum;
    }
    __syncthreads();
    int b1 = b1S;
    for (int i = tid; i < 4096; i += 256) hist[i] = 0u;
    __syncthreads();
    for (int i = tid; i < HW; i += 256) {
        unsigned k = keyS[i];
        if ((int)(k >> 20) == b1) atomicAdd(&hist[(k >> 8) & 4095], 1u);
    }
    __syncthreads();
    { unsigned s = 0; for (int j = 0; j < 16; j++) s += hist[tid * 16 + j]; pc[tid] = s; }
    __syncthreads();
    if (tid == 0) {
        unsigned cum = (unsigned)c1S; int cs_ = 255;
        for (; cs_ > 0; cs_--) { if (cum + pc[cs_] >= (unsigned)KSEL) break; cum += pc[cs_]; }
        int bb = cs_ * 16 + 15;
        for (; bb > cs_ * 16; bb--) { if (cum + hist[bb] >= (unsigned)KSEL) break; cum += hist[bb]; }
        b2S = bb;
    }
    __syncthreads();
    int b2 = b2S;
    for (int i = tid; i < HW; i += 256) {
        unsigned k = keyS[i]; int hb = (int)(k >> 20);
        if (hb > b1 || (hb == b1 && (int)((k >> 8) & 4095) >= b2)) {
            int p = atomicAdd(&lcnt, 1);
            if (p < 1024) list[p] = k;
        }
    }
    __syncthreads();
    int L = lcnt; if (L > 1024) L = 1024;
    for (int i = tid; i < L; i += 256) {
        unsigned e = list[i]; int c = 0;
        for (int j = 0; j < L; j++) c += (list[j] >= e) ? 1 : 0;
        if (c >= KSEL) atomicMax(&bestS, e);
    }
    __syncthreads();
    // slack covers cross-kernel MFMA drift (~2e-5); only ever ADDS candidates
    if (tid == 0) tau[b] = unmonof(bestS) - 3e-4f;
}

// ---- Pass C: build (row, 64-col-tile) pair lists from maxvt bound ----------
__global__ __launch_bounds__(256) void pairs_k(
    const float* __restrict__ maxvt, const float* __restrict__ lnDr,
    const float* __restrict__ minlnc, const float* __restrict__ tau,
    int* __restrict__ pairrows, int* __restrict__ paircnt)
{
    const int batch = blockIdx.z, t = blockIdx.x;
    const float tv = tau[batch] - 3e-4f;
    const float ml = minlnc[batch * NT + t];
    const float* mv = maxvt + ((size_t)batch * NT + t) * PADR;
    const float* ldr = lnDr + (size_t)batch * HW;
    int* pr = pairrows + ((size_t)batch * NT + t) * PADR;
    for (int r = threadIdx.x; r < HW; r += 256) {
        float b = 2.0f * mv[r] - ldr[r] - ml;
        if (b >= tv) {
            int p = atomicAdd(&paircnt[batch * NT + t], 1);
            pr[p] = r;
        }
    }
}

// ---- Pass D: recompute surviving pairs (16x16x32 chain), collect -----------
__global__ __launch_bounds__(256) void recollect_k(
    const unsigned short* __restrict__ hiT, const unsigned short* __restrict__ loT,
    const float* __restrict__ lnDr, const float* __restrict__ lnDc,
    const float* __restrict__ tau, const int* __restrict__ pairrows,
    const int* __restrict__ paircnt, uint2* __restrict__ cand,
    int* __restrict__ cnt)
{
    const int t = blockIdx.x, batch = blockIdx.y;
    const int pc = paircnt[batch * NT + t];
    if (pc == 0) return;
    const float tv = tau[batch];
    const int* pr = pairrows + ((size_t)batch * NT + t) * PADR;

    const unsigned short* Ah = hiT + (size_t)batch * PADR * 128;
    const unsigned short* Al = loT + (size_t)batch * PADR * 128;
    const unsigned short* Bh = hiT + (size_t)(batch + 4) * PADR * 128;
    const unsigned short* Bl = loT + (size_t)(batch + 4) * PADR * 128;

    const int tid = threadIdx.x;
    const int lane = tid & 63, w = tid >> 6;
    const int m = lane & 15, q = lane >> 4;
    const float scale = 0.078125f;

    for (int g = w; g * 16 < pc; g += 4) {
        int pi = g * 16 + m;
        int rowv = (pi < pc) ? pr[pi] : HW;
        float ldrv = (pi < pc) ? lnDr[(size_t)batch * HW + rowv] : 0.f;
        size_t arow = ((size_t)(rowv >> 7) * 16) * 1024 + (size_t)(rowv & 127) * 8;

        float4v acc[4];
#pragma unroll
        for (int i = 0; i < 4; i++) acc[i] = (float4v){0.f, 0.f, 0.f, 0.f};
#pragma unroll
        for (int k0 = 0; k0 < 128; k0 += 32) {
            int kb = (k0 >> 3) + q;
            short8 ah = *(const short8*)(Ah + arow + (size_t)kb * 1024);
            short8 al = *(const short8*)(Al + arow + (size_t)kb * 1024);
#pragma unroll
            for (int nt = 0; nt < 4; nt++) {
                int c = t * 64 + nt * 16 + m;
                size_t brow = ((size_t)(c >> 7) * 16 + kb) * 1024 + (size_t)(c & 127) * 8;
                short8 bh = *(const short8*)(Bh + brow);
                short8 bl = *(const short8*)(Bl + brow);
                acc[nt] = __builtin_amdgcn_mfma_f32_16x16x32_bf16(ah, bh, acc[nt], 0, 0, 0);
                acc[nt] = __builtin_amdgcn_mfma_f32_16x16x32_bf16(ah, bl, acc[nt], 0, 0, 0);
                acc[nt] = __builtin_amdgcn_mfma_f32_16x16x32_bf16(al, bh, acc[nt], 0, 0, 0);
            }
        }
#pragma unroll
        for (int nt = 0; nt < 4; nt++) {
            int c = t * 64 + nt * 16 + m;
            if (c >= HW) continue;
            float ldc = lnDc[(size_t)batch * HW + c];
#pragma unroll
            for (int r = 0; r < 4; r++) {
                int ri = q * 4 + r;
                if (g * 16 + ri >= pc) continue;
                int rowo = __shfl(rowv, ri);
                float ldro = __shfl(ldrv, ri);
                float v = acc[nt][r] * scale;
                float tt = 2.0f * v - ldro - ldc;
                if (tt >= tv) {
                    int p = atomicAdd(&cnt[batch], 1);
                    if (p < CAP)
                        cand[(size_t)batch * CAP + p] =
                            make_uint2(monof(tt), (unsigned)(rowo * HW + c));
                }
            }
        }
    }
}

// ---- Pass E: exact ordered top-100: 2-level hist prefilter + rank ----------
__global__ __launch_bounds__(256) void select_k(
    const uint2* __restrict__ cand, const int* __restrict__ cnt,
    const float* __restrict__ W,
    float* __restrict__ C0, float* __restrict__ C1,
    float* __restrict__ Sx, float* __restrict__ Sy)
{
    const int batch = blockIdx.z, tid = threadIdx.x;
    const uint2* cb = cand + (size_t)batch * CAP;
    int M = cnt[batch]; if (M > CAP) M = CAP;

    __shared__ unsigned hist[4096];
    __shared__ unsigned pc[256];
    __shared__ int b1S, c1S, b2S, lcnt;
    __shared__ U64 list[512];
    __shared__ int topiS[KSEL];
    __shared__ float cx0S[KSEL], cy0S[KSEL], cx1S[KSEL], cy1S[KSEL];

    for (int i = tid; i < 4096; i += 256) hist[i] = 0u;
    if (tid == 0) lcnt = 0;
    __syncthreads();
    for (int i = tid; i < M; i += 256) atomicAdd(&hist[cb[i].x >> 20], 1u);
    __syncthreads();
    { unsigned s = 0; for (int j = 0; j < 16; j++) s += hist[tid * 16 + j]; pc[tid] = s; }
    __syncthreads();
    if (tid == 0) {
        unsigned cum = 0; int cs_ = 255;
        for (; cs_ > 0; cs_--) { if (cum + pc[cs_] >= (unsigned)KSEL) break; cum += pc[cs_]; }
        int bb = cs_ * 16 + 15;
        for (; bb > cs_ * 16; bb--) { if (cum + hist[bb] >= (unsigned)KSEL) break; cum += hist[bb]; }
        b1S = bb; c1S = (int)cum;
    }
    __syncthreads();
    int b1 = b1S;
    for (int i = tid; i < 4096; i += 256) hist[i] = 0u;
    __syncthreads();
    for (int i = tid; i < M; i += 256) {
        unsigned k = cb[i].x;
        if ((int)(k >> 20) == b1) atomicAdd(&hist[(k >> 8) & 4095], 1u);
    }
    __syncthreads();
    { unsigned s = 0; for (int j = 0; j < 16; j++) s += hist[tid * 16 + j]; pc[tid] = s; }
    __syncthreads();
    if (tid == 0) {
        unsigned cum = (unsigned)c1S; int cs_ = 255;
        for (; cs_ > 0; cs_--) { if (cum + pc[cs_] >= (unsigned)KSEL) break; cum += pc[cs_]; }
        int bb = cs_ * 16 + 15;
        for (; bb > cs_ * 16; bb--) { if (cum + hist[bb] >= (unsigned)KSEL) break; cum += hist[bb]; }
        b2S = bb;
    }
    __syncthreads();
    int b2 = b2S;
    for (int i = tid; i < M; i += 256) {
        uint2 e = cb[i];
        int hb = (int)(e.x >> 20);
        if (hb > b1 || (hb == b1 && (int)((e.x >> 8) & 4095) >= b2)) {
            int p = atomicAdd(&lcnt, 1);
            if (p < 512) list[p] = ((U64)e.x << 32) | (unsigned)(~e.y);
        }
    }
    __syncthreads();
    int L = lcnt; if (L > 512) L = 512;
    for (int i = tid; i < L; i += 256) {
        U64 e = list[i]; int r = 0;
        for (int j = 0; j < L; j++) r += (list[j] > e) ? 1 : 0;   // unique keys
        if (r < KSEL) topiS[r] = (int)(~(unsigned)(e & 0xffffffffu));
    }
    __syncthreads();

    if (tid < KSEL) {
        int idx = topiS[tid];
        int qq = idx / HW, rr = idx - qq * HW;
        cx0S[tid] = (float)(qq % 60) / 60.0f;
        cy0S[tid] = (float)(qq / 60) / 60.0f;
        cx1S[tid] = (float)(rr % 60) / 60.0f;
        cy1S[tid] = (float)(rr / 60) / 60.0f;
    }
    __syncthreads();
    if (tid < 128) {
        const float* wr_ = W + tid * 200;
        float c0 = 0.f, c1 = 0.f, sx = 0.f, sy = 0.f;
        for (int k = 0; k < KSEL; k++) {
            float wx = wr_[2 * k], wy = wr_[2 * k + 1];
            c0 += cx0S[k] * wx + cy0S[k] * wy;
            c1 += cx1S[k] * wx + cy1S[k] * wy;
            sx += wx; sy += wy;
        }
        C0[batch * 128 + tid] = c0;
        C1[batch * 128 + tid] = c1;
        if (batch == 0) { Sx[tid] = sx; Sy[tid] = sy; }
    }
}

// ---- Pass F: out = x + affine emb (elementwise) ----------------------------
__global__ __launch_bounds__(256) void final_k(
    const float* __restrict__ x, const float* __restrict__ bias,
    const float* __restrict__ C0, const float* __restrict__ C1,
    const float* __restrict__ Sx, const float* __restrict__ Sy,
    float* __restrict__ out)
{
    int bd = blockIdx.x;
    int b = bd >> 7, d = bd & 127;
    float cst = bias[d] - ((b < 4) ? C0[b * 128 + d] : C1[(b - 4) * 128 + d]);
    float sx = Sx[d], sy = Sy[d];
    const float4* xin = (const float4*)(x + (size_t)bd * HW);
    float4* o4 = (float4*)(out + (size_t)bd * HW);
    for (int f = threadIdx.x; f < NF4; f += 256) {
        float4 v = xin[f];
        int p0 = f * 4;
        float gy = (float)(p0 / 60) / 60.0f;
        float gxb = (float)(p0 % 60);
        float add = cst + gy * sy;
        v.x += add + ((gxb       ) / 60.0f) * sx;
        v.y += add + ((gxb + 1.f) / 60.0f) * sx;
        v.z += add + ((gxb + 2.f) / 60.0f) * sx;
        v.w += add + ((gxb + 3.f) / 60.0f) * sx;
        o4[f] = v;
    }
}

extern "C" void kernel_launch(void* const* d_in, const int* in_sizes, int n_in,
                              void* d_out, int out_size, void* d_ws, size_t ws_size,
                              hipStream_t stream)
{
    const float* x    = (const float*)d_in[0];
    const float* W    = (const float*)d_in[1];
    const float* bias = (const float*)d_in[2];
    float* out = (float*)d_out;

    char* ws = (char*)d_ws;
    float*    den     = (float*)(ws + 0);          // den_row[4][HW] + den_col[4][HW] = 115200
    float*    den_row = den;
    float*    den_col = (float*)(ws + 57600);
    float*    lnD     = (float*)(ws + 115200);     // 115200 -> 230400
    float*    lnDr    = lnD;
    float*    lnDc    = (float*)(ws + 172800);
    int*      cnt     = (int*)  (ws + 230400);     // 16
    float*    tau     = (float*)(ws + 230416);     // 16 -> 230432
    float*    minlnc  = (float*)(ws + 230432);     // 928 -> 231360
    float*    maxlnc  = (float*)(ws + 231360);     // 928 -> 232288
    int*      paircnt = (int*)  (ws + 232288);     // 928 -> 233216
    float*    keylb   = (float*)(ws + 233216);     // 57600 -> 290816
    float*    C0      = (float*)(ws + 290816);     // -> 292864
    float*    C1      = (float*)(ws + 292864);     // -> 294912
    float*    Sx      = (float*)(ws + 294912);     // -> 295424
    float*    Sy      = (float*)(ws + 295424);     // -> 295936
    uint2*    cand    = (uint2*)(ws + 295936);     // 524288 -> 820224
    int*      pairrows= (int*)  (ws + 820224);     // 3444736 -> 4264960
    float*    maxvt   = (float*)(ws + 4264960);    // 3444736 -> 7709696
    unsigned short* hiT = (unsigned short*)(ws + 7709696);   // 7602176 -> 15311872
    unsigned short* loT = (unsigned short*)(ws + 15311872);  // 7602176 -> 22914048

    hipMemsetAsync(ws, 0, 115200, stream);          // den
    hipMemsetAsync(ws + 230400, 0, 32, stream);     // cnt + tau
    hipMemsetAsync(ws + 232288, 0, 928, stream);    // paircnt

    conv_k     <<<dim3(58, 2, 8),  256, 0, stream>>>(x, hiT, loT);
    gemm_mfma_k<<<dim3(29, 29, 4), 256, 0, stream>>>(hiT, loT, den_row, den_col, maxvt);
    logs_k     <<<dim3(113),       256, 0, stream>>>(den, lnD);
    tilestat_k <<<dim3(NT, 1, 4),   64, 0, stream>>>(lnDc, minlnc, maxlnc);
    keylb_k    <<<dim3(15, 1, 4),  256, 0, stream>>>(maxvt, lnDr, maxlnc, keylb);
    tau_k      <<<dim3(1, 1, 4),   256, 0, stream>>>(keylb, tau);
    pairs_k    <<<dim3(NT, 1, 4),  256, 0, stream>>>(maxvt, lnDr, minlnc, tau, pairrows, paircnt);
    recollect_k<<<dim3(NT, 4),     256, 0, stream>>>(hiT, loT, lnDr, lnDc, tau, pairrows, paircnt, cand, cnt);
    select_k   <<<dim3(1, 1, 4),   256, 0, stream>>>(cand, cnt, W, C0, C1, Sx, Sy);
    final_k    <<<dim3(1024),      256, 0, stream>>>(x, bias, C0, C1, Sx, Sy, out);
}

// Round 7
// 229.866 us; speedup vs baseline: 1.5192x; 1.1442x over previous
//
#include <hip/hip_runtime.h>

#define HW 3600
#define PADR 3712            // 29*128 padded rows
#define NF4 900
#define CAP 16384
#define KSEL 100
#define NT 58                // 64-col tiles
typedef unsigned long long U64;

using short8   = __attribute__((ext_vector_type(8))) short;
using float4v  = __attribute__((ext_vector_type(4))) float;
using float16v = __attribute__((ext_vector_type(16))) float;

__device__ __forceinline__ unsigned monof(float f) {
    unsigned b = __float_as_uint(f);
    return (b & 0x80000000u) ? ~b : (b | 0x80000000u);
}
__device__ __forceinline__ float unmonof(unsigned m) {
    return __uint_as_float((m & 0x80000000u) ? (m ^ 0x80000000u) : ~m);
}
__device__ __forceinline__ unsigned short f2bf(float f) {   // RNE
    unsigned b = __float_as_uint(f);
    return (unsigned short)((b + 0x7FFFu + ((b >> 16) & 1u)) >> 16);
}
__device__ __forceinline__ float bf2f(unsigned short h) {
    return __uint_as_float(((unsigned)h) << 16);
}
__device__ __forceinline__ void async16(const void* g, void* l) {
    __builtin_amdgcn_global_load_lds((const __attribute__((address_space(1))) void*)g,
                                     (__attribute__((address_space(3))) void*)l, 16, 0, 0);
}

// chunk-major element address (in shorts): buf[b][rblk][kb][row128][8]

// ---- Pass 0: convert x (b,d,l) -> chunk-major split-bf16 hiT/loT -----------
__global__ __launch_bounds__(256) void conv_k(
    const float* __restrict__ x,
    unsigned short* __restrict__ hiT, unsigned short* __restrict__ loT)
{
    int b = blockIdx.z, l0 = blockIdx.x * 64, d0 = blockIdx.y * 64;
    __shared__ float t[64][65];
    int tid = threadIdx.x;
#pragma unroll
    for (int r = 0; r < 4; r++) {
        int idx = tid + 256 * r;              // 1024 float4 slots
        int d = idx >> 4, lq = idx & 15;
        int l = l0 + lq * 4;
        const float* src = x + ((size_t)b * 128 + d0 + d) * HW;
        float4 v;
        if (l + 3 < HW) v = *(const float4*)(src + l);
        else {
            v.x = (l     < HW) ? src[l]     : 0.f;
            v.y = (l + 1 < HW) ? src[l + 1] : 0.f;
            v.z = (l + 2 < HW) ? src[l + 2] : 0.f;
            v.w = (l + 3 < HW) ? src[l + 3] : 0.f;
        }
        t[lq * 4 + 0][d] = v.x; t[lq * 4 + 1][d] = v.y;
        t[lq * 4 + 2][d] = v.z; t[lq * 4 + 3][d] = v.w;
    }
    __syncthreads();
    const int rblk = l0 >> 7;
#pragma unroll
    for (int r = 0; r < 2; r++) {
        int idx = tid + 256 * r;              // 512 chunks of 8 bf16
        int l = idx & 63, dq = idx >> 6;      // row-inner -> coalesced stores
        unsigned hp[4], lp[4];
#pragma unroll
        for (int j = 0; j < 4; j++) {
            float f0 = t[l][dq * 8 + 2 * j], f1 = t[l][dq * 8 + 2 * j + 1];
            unsigned short h0 = f2bf(f0), h1 = f2bf(f1);
            unsigned short g0 = f2bf(f0 - bf2f(h0)), g1 = f2bf(f1 - bf2f(h1));
            hp[j] = (unsigned)h0 | ((unsigned)h1 << 16);
            lp[j] = (unsigned)g0 | ((unsigned)g1 << 16);
        }
        size_t o = ((size_t)(b * 29 + rblk) * 16 + (d0 >> 3) + dq) * 1024
                 + (size_t)((l0 + l) & 127) * 8;
        *(uint4*)(hiT + o) = make_uint4(hp[0], hp[1], hp[2], hp[3]);
        *(uint4*)(loT + o) = make_uint4(lp[0], lp[1], lp[2], lp[3]);
    }
}

// ---- Pass A: LDS-staged 32x32x16 split-bf16 GEMM; transpose-LDS epilogue ---
__global__ __launch_bounds__(256) void gemm_mfma_k(
    const unsigned short* __restrict__ hiT, const unsigned short* __restrict__ loT,
    float* __restrict__ den_row, float* __restrict__ den_col,
    float* __restrict__ maxvt)
{
    const int batch = blockIdx.z, bx = blockIdx.x, by = blockIdx.y;
    __shared__ __align__(16) unsigned char smem[34816];
    unsigned short (*stage)[4][128][8] = (unsigned short (*)[4][128][8])smem;

    const int tid = threadIdx.x;
    const int lane = tid & 63, w = tid >> 6;
    const int wr = w >> 1, wc = w & 1;
    const int l31 = lane & 31, h = lane >> 5;

    const unsigned short* psrc = (w == 0) ? hiT : (w == 1) ? loT : (w == 2) ? hiT : loT;
    const int bsel = (w < 2) ? batch : batch + 4;
    const int rblk = (w < 2) ? by : bx;
    const size_t cbase = ((size_t)(bsel * 29 + rblk) * 16) * 1024;

    float16v acc[2][2];
#pragma unroll
    for (int i = 0; i < 2; i++)
#pragma unroll
        for (int j = 0; j < 2; j++) acc[i][j] = (float16v)(0.f);

    for (int k0 = 0; k0 < 128; k0 += 32) {
#pragma unroll
        for (int i = 0; i < 8; i++) {
            int kb = i >> 1, half = i & 1;
            const unsigned short* g = psrc + cbase + (size_t)((k0 >> 3) + kb) * 1024
                                    + (half << 9) + lane * 8;
            async16(g, &stage[w][kb][half << 6][0]);
        }
        __syncthreads();
#pragma unroll
        for (int j = 0; j < 2; j++) {
            int kb = j * 2 + h;
            short8 ah[2], al[2], bh[2], bl[2];
#pragma unroll
            for (int t = 0; t < 2; t++) {
                ah[t] = *(const short8*)&stage[0][kb][wr * 64 + t * 32 + l31][0];
                al[t] = *(const short8*)&stage[1][kb][wr * 64 + t * 32 + l31][0];
                bh[t] = *(const short8*)&stage[2][kb][wc * 64 + t * 32 + l31][0];
                bl[t] = *(const short8*)&stage[3][kb][wc * 64 + t * 32 + l31][0];
            }
#pragma unroll
            for (int mt = 0; mt < 2; mt++)
#pragma unroll
                for (int nt = 0; nt < 2; nt++) {
                    acc[mt][nt] = __builtin_amdgcn_mfma_f32_32x32x16_bf16(ah[mt], bh[nt], acc[mt][nt], 0, 0, 0);
                    acc[mt][nt] = __builtin_amdgcn_mfma_f32_32x32x16_bf16(ah[mt], bl[nt], acc[mt][nt], 0, 0, 0);
                    acc[mt][nt] = __builtin_amdgcn_mfma_f32_32x32x16_bf16(al[mt], bh[nt], acc[mt][nt], 0, 0, 0);
                }
        }
        __syncthreads();   // also frees stage for epilogue reuse
    }

    // ---- epilogue: per-wave LDS transpose (reuses stage; wave-private) ----
    // C/D layout: col = lane&31 (+32*nt), row = (reg&3)+8*(reg>>2)+4*h (+32*mt)
    const float scale = 0.078125f;   // 1/(128*0.1)
    float* T = ((float*)smem) + w * (64 * 34);
    const bool interior = (bx < 28) && (by < 28);
    const int col0 = bx * 128 + wc * 64 + l31;       // nt=0
    const bool c0v = interior || (col0 < HW);
    const bool c1v = interior || (col0 + 32 < HW);
    float cs0 = 0.f, cs1 = 0.f;

    // Phase A: row sums of exp
#pragma unroll
    for (int mt = 0; mt < 2; mt++)
#pragma unroll
        for (int reg = 0; reg < 16; reg++) {
            float v0 = acc[mt][0][reg] * scale;
            float v1 = acc[mt][1][reg] * scale;
            float e0 = c0v ? __expf(v0) : 0.f;
            float e1 = c1v ? __expf(v1) : 0.f;
            int row64 = mt * 32 + (reg & 3) + 8 * (reg >> 2) + 4 * h;
            bool rv = interior || (by * 128 + wr * 64 + row64 < HW);
            if (rv) { cs0 += e0; cs1 += e1; }
            T[row64 * 34 + l31] = e0 + e1;
        }
    __asm__ __volatile__("s_waitcnt lgkmcnt(0)" ::: "memory");
    float rsum = 0.f;
#pragma unroll
    for (int i = 0; i < 16; i++) {
        float2 p = *(const float2*)&T[lane * 34 + 2 * i];
        rsum += p.x + p.y;
    }
    __asm__ __volatile__("s_waitcnt lgkmcnt(0)" ::: "memory");
    const int lrow = by * 128 + wr * 64 + lane;
    const bool rowv = interior || (lrow < HW);
    if (rowv) atomicAdd(&den_row[(size_t)batch * HW + lrow], rsum);

    // Phase B: row max of v over this wave's 64 cols -> maxvt[ct][row]
#pragma unroll
    for (int mt = 0; mt < 2; mt++)
#pragma unroll
        for (int reg = 0; reg < 16; reg++) {
            float m0 = c0v ? acc[mt][0][reg] : -3.4e38f;
            float m1 = c1v ? acc[mt][1][reg] : -3.4e38f;
            int row64 = mt * 32 + (reg & 3) + 8 * (reg >> 2) + 4 * h;
            T[row64 * 34 + l31] = fmaxf(m0, m1) * scale;
        }
    __asm__ __volatile__("s_waitcnt lgkmcnt(0)" ::: "memory");
    float rmax = -3.4e38f;
#pragma unroll
    for (int i = 0; i < 16; i++) {
        float2 p = *(const float2*)&T[lane * 34 + 2 * i];
        rmax = fmaxf(rmax, fmaxf(p.x, p.y));
    }
    const int ct = bx * 2 + wc;
    if (rowv) maxvt[((size_t)batch * NT + ct) * PADR + lrow] = rmax;

    // col sums: combine the two h row-halves, then global atomic
    cs0 += __shfl_xor(cs0, 32);
    cs1 += __shfl_xor(cs1, 32);
    if (h == 0) {
        if (c0v) atomicAdd(&den_col[(size_t)batch * HW + col0], cs0);
        if (c1v) atomicAdd(&den_col[(size_t)batch * HW + col0 + 32], cs1);
    }
}

// ---- Pass B: merged tilestat + keylb ---------------------------------------
// keylb[j] = max_t (2*maxvt[t][j] - maxlnc[t]) - ln(den_row[j])
__global__ __launch_bounds__(256) void stat_k(
    const float* __restrict__ den_row, const float* __restrict__ den_col,
    const float* __restrict__ maxvt, float* __restrict__ keylb)
{
    const int b = blockIdx.z, tid = threadIdx.x;
    __shared__ float lncS[HW];
    __shared__ float mlsS[NT];
    for (int i = tid; i < HW; i += 256)
        lncS[i] = __logf(den_col[(size_t)b * HW + i]);
    __syncthreads();
    if (tid < NT) {
        float mx = -3.4e38f;
        int s0 = tid * 64, s1 = s0 + 64; if (s1 > HW) s1 = HW;
        for (int s = s0; s < s1; s++) mx = fmaxf(mx, lncS[s]);
        if (s0 >= HW) mx = 1e30f;             // empty tile 57
        mlsS[tid] = mx;
    }
    __syncthreads();
    int j = blockIdx.x * 240 + tid;
    if (tid < 240 && j < HW) {
        float best = -3.4e38f;
#pragma unroll 2
        for (int t = 0; t < NT; t++)
            best = fmaxf(best, 2.0f * maxvt[((size_t)b * NT + t) * PADR + j] - mlsS[t]);
        keylb[(size_t)b * HW + j] = best - __logf(den_row[(size_t)b * HW + j]);
    }
}

// ---- Pass C: exact 100th-largest keylb via 2-level hist + rank -> tau ------
__global__ __launch_bounds__(256) void tau_k(
    const float* __restrict__ keylb, float* __restrict__ tau)
{
    const int b = blockIdx.z, tid = threadIdx.x;
    __shared__ unsigned keyS[HW];
    __shared__ unsigned hist[4096];
    __shared__ unsigned pc[256];
    __shared__ int b1S, c1S, b2S, lcnt;
    __shared__ unsigned bestS;
    __shared__ unsigned list[1024];

    for (int i = tid; i < 4096; i += 256) hist[i] = 0u;
    if (tid == 0) { lcnt = 0; bestS = 0u; }
    __syncthreads();
    for (int i = tid; i < HW; i += 256) {
        unsigned k = monof(keylb[(size_t)b * HW + i]);
        keyS[i] = k;
        atomicAdd(&hist[k >> 20], 1u);
    }
    __syncthreads();
    { unsigned s = 0; for (int j = 0; j < 16; j++) s += hist[tid * 16 + j]; pc[tid] = s; }
    __syncthreads();
    if (tid == 0) {
        unsigned cum = 0; int cs_ = 255;
        for (; cs_ > 0; cs_--) { if (cum + pc[cs_] >= (unsigned)KSEL) break; cum += pc[cs_]; }
        int bb = cs_ * 16 + 15;
        for (; bb > cs_ * 16; bb--) { if (cum + hist[bb] >= (unsigned)KSEL) break; cum += hist[bb]; }
        b1S = bb; c1S = (int)cum;
    }
    __syncthreads();
    int b1 = b1S;
    for (int i = tid; i < 4096; i += 256) hist[i] = 0u;
    __syncthreads();
    for (int i = tid; i < HW; i += 256) {
        unsigned k = keyS[i];
        if ((int)(k >> 20) == b1) atomicAdd(&hist[(k >> 8) & 4095], 1u);
    }
    __syncthreads();
    { unsigned s = 0; for (int j = 0; j < 16; j++) s += hist[tid * 16 + j]; pc[tid] = s; }
    __syncthreads();
    if (tid == 0) {
        unsigned cum = (unsigned)c1S; int cs_ = 255;
        for (; cs_ > 0; cs_--) { if (cum + pc[cs_] >= (unsigned)KSEL) break; cum += pc[cs_]; }
        int bb = cs_ * 16 + 15;
        for (; bb > cs_ * 16; bb--) { if (cum + hist[bb] >= (unsigned)KSEL) break; cum += hist[bb]; }
        b2S = bb;
    }
    __syncthreads();
    int b2 = b2S;
    for (int i = tid; i < HW; i += 256) {
        unsigned k = keyS[i]; int hb = (int)(k >> 20);
        if (hb > b1 || (hb == b1 && (int)((k >> 8) & 4095) >= b2)) {
            int p = atomicAdd(&lcnt, 1);
            if (p < 1024) list[p] = k;
        }
    }
    __syncthreads();
    int L = lcnt; if (L > 1024) L = 1024;
    for (int i = tid; i < L; i += 256) {
        unsigned e = list[i]; int c = 0;
        for (int j = 0; j < L; j++) c += (list[j] >= e) ? 1 : 0;
        if (c >= KSEL) atomicMax(&bestS, e);
    }
    __syncthreads();
    // slack covers cross-kernel MFMA drift; only ever ADDS candidates
    if (tid == 0) tau[b] = unmonof(bestS) - 3e-4f;
}

// ---- Pass D: merged pairs + recompute + collect ----------------------------
__global__ __launch_bounds__(256) void recollect_k(
    const unsigned short* __restrict__ hiT, const unsigned short* __restrict__ loT,
    const float* __restrict__ den_row, const float* __restrict__ den_col,
    const float* __restrict__ maxvt, const float* __restrict__ tau,
    uint2* __restrict__ cand, int* __restrict__ cnt)
{
    const int t = blockIdx.x, batch = blockIdx.y;
    const int tid = threadIdx.x;
    __shared__ float lnrS[HW];
    __shared__ float lncS[64];
    __shared__ int prS[HW];
    __shared__ int pcS;
    __shared__ float mnlS;

    if (tid < 64) {
        int c = t * 64 + tid;
        float lc = (c < HW) ? __logf(den_col[(size_t)batch * HW + c]) : 1e30f;
        lncS[tid] = lc;
        float mn = lc;
#pragma unroll
        for (int off = 1; off < 64; off <<= 1) mn = fminf(mn, __shfl_xor(mn, off));
        if (tid == 0) mnlS = mn;
    }
    for (int r = tid; r < HW; r += 256)
        lnrS[r] = __logf(den_row[(size_t)batch * HW + r]);
    if (tid == 0) pcS = 0;
    __syncthreads();

    const float tv = tau[batch];
    const float tvm = tv - 3e-4f;
    const float mnl = mnlS;
    const float* mv = maxvt + ((size_t)batch * NT + t) * PADR;
    for (int r = tid; r < HW; r += 256) {
        float bnd = 2.0f * mv[r] - lnrS[r] - mnl;
        if (bnd >= tvm) {
            int p = atomicAdd(&pcS, 1);
            prS[p] = r;
        }
    }
    __syncthreads();
    const int pc = pcS;
    if (pc == 0) return;

    const unsigned short* Ah = hiT + 0;
    const unsigned short* Al = loT + 0;
    // chunk-major: batch offset folded into cbase arithmetic below
    const int lane = tid & 63, w = tid >> 6;
    const int m = lane & 15, q = lane >> 4;
    const float scale = 0.078125f;
    const size_t abase = (size_t)batch * PADR * 128;        // in shorts (29*16*1024)
    const size_t bbase = (size_t)(batch + 4) * PADR * 128;

    for (int g = w; g * 16 < pc; g += 4) {
        int pi = g * 16 + m;
        int rowv = (pi < pc) ? prS[pi] : HW;      // pad rows are zeros
        float ldrv = (pi < pc) ? lnrS[rowv] : 0.f;
        size_t arow = abase + ((size_t)(rowv >> 7) * 16) * 1024 + (size_t)(rowv & 127) * 8;

        float4v acc[4];
#pragma unroll
        for (int i = 0; i < 4; i++) acc[i] = (float4v){0.f, 0.f, 0.f, 0.f};
#pragma unroll
        for (int k0 = 0; k0 < 128; k0 += 32) {
            int kb = (k0 >> 3) + q;
            short8 ah = *(const short8*)(Ah + arow + (size_t)kb * 1024);
            short8 al = *(const short8*)(Al + arow + (size_t)kb * 1024);
#pragma unroll
            for (int nt = 0; nt < 4; nt++) {
                int c = t * 64 + nt * 16 + m;
                size_t brow = bbase + ((size_t)(c >> 7) * 16 + kb) * 1024 + (size_t)(c & 127) * 8;
                short8 bh = *(const short8*)(hiT + brow);
                short8 bl = *(const short8*)(loT + brow);
                acc[nt] = __builtin_amdgcn_mfma_f32_16x16x32_bf16(ah, bh, acc[nt], 0, 0, 0);
                acc[nt] = __builtin_amdgcn_mfma_f32_16x16x32_bf16(ah, bl, acc[nt], 0, 0, 0);
                acc[nt] = __builtin_amdgcn_mfma_f32_16x16x32_bf16(al, bh, acc[nt], 0, 0, 0);
            }
        }
#pragma unroll
        for (int nt = 0; nt < 4; nt++) {
            int c = t * 64 + nt * 16 + m;
            if (c >= HW) continue;
            float ldc = lncS[nt * 16 + m];
#pragma unroll
            for (int r = 0; r < 4; r++) {
                int ri = q * 4 + r;
                if (g * 16 + ri >= pc) continue;
                int rowo = __shfl(rowv, ri);
                float ldro = __shfl(ldrv, ri);
                float v = acc[nt][r] * scale;
                float tt = 2.0f * v - ldro - ldc;
                if (tt >= tv) {
                    int p = atomicAdd(&cnt[batch], 1);
                    if (p < CAP)
                        cand[(size_t)batch * CAP + p] =
                            make_uint2(monof(tt), (unsigned)(rowo * HW + c));
                }
            }
        }
    }
}

// ---- Pass E: exact ordered top-100: 2-level hist prefilter + rank ----------
__global__ __launch_bounds__(256) void select_k(
    const uint2* __restrict__ cand, const int* __restrict__ cnt,
    const float* __restrict__ W,
    float* __restrict__ C0, float* __restrict__ C1,
    float* __restrict__ Sx, float* __restrict__ Sy)
{
    const int batch = blockIdx.z, tid = threadIdx.x;
    const uint2* cb = cand + (size_t)batch * CAP;
    int M = cnt[batch]; if (M > CAP) M = CAP;

    __shared__ unsigned hist[4096];
    __shared__ unsigned pc[256];
    __shared__ int b1S, c1S, b2S, lcnt;
    __shared__ U64 list[512];
    __shared__ int topiS[KSEL];
    __shared__ float cx0S[KSEL], cy0S[KSEL], cx1S[KSEL], cy1S[KSEL];

    for (int i = tid; i < 4096; i += 256) hist[i] = 0u;
    if (tid == 0) lcnt = 0;
    __syncthreads();
    for (int i = tid; i < M; i += 256) atomicAdd(&hist[cb[i].x >> 20], 1u);
    __syncthreads();
    { unsigned s = 0; for (int j = 0; j < 16; j++) s += hist[tid * 16 + j]; pc[tid] = s; }
    __syncthreads();
    if (tid == 0) {
        unsigned cum = 0; int cs_ = 255;
        for (; cs_ > 0; cs_--) { if (cum + pc[cs_] >= (unsigned)KSEL) break; cum += pc[cs_]; }
        int bb = cs_ * 16 + 15;
        for (; bb > cs_ * 16; bb--) { if (cum + hist[bb] >= (unsigned)KSEL) break; cum += hist[bb]; }
        b1S = bb; c1S = (int)cum;
    }
    __syncthreads();
    int b1 = b1S;
    for (int i = tid; i < 4096; i += 256) hist[i] = 0u;
    __syncthreads();
    for (int i = tid; i < M; i += 256) {
        unsigned k = cb[i].x;
        if ((int)(k >> 20) == b1) atomicAdd(&hist[(k >> 8) & 4095], 1u);
    }
    __syncthreads();
    { unsigned s = 0; for (int j = 0; j < 16; j++) s += hist[tid * 16 + j]; pc[tid] = s; }
    __syncthreads();
    if (tid == 0) {
        unsigned cum = (unsigned)c1S; int cs_ = 255;
        for (; cs_ > 0; cs_--) { if (cum + pc[cs_] >= (unsigned)KSEL) break; cum += pc[cs_]; }
        int bb = cs_ * 16 + 15;
        for (; bb > cs_ * 16; bb--) { if (cum + hist[bb] >= (unsigned)KSEL) break; cum += hist[bb]; }
        b2S = bb;
    }
    __syncthreads();
    int b2 = b2S;
    for (int i = tid; i < M; i += 256) {
        uint2 e = cb[i];
        int hb = (int)(e.x >> 20);
        if (hb > b1 || (hb == b1 && (int)((e.x >> 8) & 4095) >= b2)) {
            int p = atomicAdd(&lcnt, 1);
            if (p < 512) list[p] = ((U64)e.x << 32) | (unsigned)(~e.y);
        }
    }
    __syncthreads();
    int L = lcnt; if (L > 512) L = 512;
    for (int i = tid; i < L; i += 256) {
        U64 e = list[i]; int r = 0;
        for (int j = 0; j < L; j++) r += (list[j] > e) ? 1 : 0;   // unique keys
        if (r < KSEL) topiS[r] = (int)(~(unsigned)(e & 0xffffffffu));
    }
    __syncthreads();

    if (tid < KSEL) {
        int idx = topiS[tid];
        int qq = idx / HW, rr = idx - qq * HW;
        cx0S[tid] = (float)(qq % 60) / 60.0f;
        cy0S[tid] = (float)(qq / 60) / 60.0f;
        cx1S[tid] = (float)(rr % 60) / 60.0f;
        cy1S[tid] = (float)(rr / 60) / 60.0f;
    }
    __syncthreads();
    if (tid < 128) {
        const float* wr_ = W + tid * 200;
        float c0 = 0.f, c1 = 0.f, sx = 0.f, sy = 0.f;
        for (int k = 0; k < KSEL; k++) {
            float wx = wr_[2 * k], wy = wr_[2 * k + 1];
            c0 += cx0S[k] * wx + cy0S[k] * wy;
            c1 += cx1S[k] * wx + cy1S[k] * wy;
            sx += wx; sy += wy;
        }
        C0[batch * 128 + tid] = c0;
        C1[batch * 128 + tid] = c1;
        if (batch == 0) { Sx[tid] = sx; Sy[tid] = sy; }
    }
}

// ---- Pass F: out = x + affine emb (elementwise) ----------------------------
__global__ __launch_bounds__(256) void final_k(
    const float* __restrict__ x, const float* __restrict__ bias,
    const float* __restrict__ C0, const float* __restrict__ C1,
    const float* __restrict__ Sx, const float* __restrict__ Sy,
    float* __restrict__ out)
{
    int bd = blockIdx.x;
    int b = bd >> 7, d = bd & 127;
    float cst = bias[d] - ((b < 4) ? C0[b * 128 + d] : C1[(b - 4) * 128 + d]);
    float sx = Sx[d], sy = Sy[d];
    const float4* xin = (const float4*)(x + (size_t)bd * HW);
    float4* o4 = (float4*)(out + (size_t)bd * HW);
    for (int f = threadIdx.x; f < NF4; f += 256) {
        float4 v = xin[f];
        int p0 = f * 4;
        float gy = (float)(p0 / 60) / 60.0f;
        float gxb = (float)(p0 % 60);
        float add = cst + gy * sy;
        v.x += add + ((gxb       ) / 60.0f) * sx;
        v.y += add + ((gxb + 1.f) / 60.0f) * sx;
        v.z += add + ((gxb + 2.f) / 60.0f) * sx;
        v.w += add + ((gxb + 3.f) / 60.0f) * sx;
        o4[f] = v;
    }
}

extern "C" void kernel_launch(void* const* d_in, const int* in_sizes, int n_in,
                              void* d_out, int out_size, void* d_ws, size_t ws_size,
                              hipStream_t stream)
{
    const float* x    = (const float*)d_in[0];
    const float* W    = (const float*)d_in[1];
    const float* bias = (const float*)d_in[2];
    float* out = (float*)d_out;

    char* ws = (char*)d_ws;
    float*    den_row = (float*)(ws + 0);          // 57600
    float*    den_col = (float*)(ws + 57600);      // -> 115200
    int*      cnt     = (int*)  (ws + 115200);     // 16
    float*    tau     = (float*)(ws + 115216);     // 16 -> 115232  (one memset)
    float*    keylb   = (float*)(ws + 115264);     // 57600 -> 172864
    float*    C0      = (float*)(ws + 172864);     // -> 174912
    float*    C1      = (float*)(ws + 174912);     // -> 176960
    float*    Sx      = (float*)(ws + 176960);     // -> 177472
    float*    Sy      = (float*)(ws + 177472);     // -> 177984
    uint2*    cand    = (uint2*)(ws + 178048);     // 524288 -> 702336
    float*    maxvt   = (float*)(ws + 702336);     // 3444736 -> 4147072
    unsigned short* hiT = (unsigned short*)(ws + 4147072);   // 7602176 -> 11749248
    unsigned short* loT = (unsigned short*)(ws + 11749248);  // 7602176 -> 19351424

    hipMemsetAsync(ws, 0, 115232, stream);          // den_row+den_col+cnt+tau

    conv_k     <<<dim3(58, 2, 8),  256, 0, stream>>>(x, hiT, loT);
    gemm_mfma_k<<<dim3(29, 29, 4), 256, 0, stream>>>(hiT, loT, den_row, den_col, maxvt);
    stat_k     <<<dim3(15, 1, 4),  256, 0, stream>>>(den_row, den_col, maxvt, keylb);
    tau_k      <<<dim3(1, 1, 4),   256, 0, stream>>>(keylb, tau);
    recollect_k<<<dim3(NT, 4),     256, 0, stream>>>(hiT, loT, den_row, den_col, maxvt, tau, cand, cnt);
    select_k   <<<dim3(1, 1, 4),   256, 0, stream>>>(cand, cnt, W, C0, C1, Sx, Sy);
    final_k    <<<dim3(1024),      256, 0, stream>>>(x, bias, C0, C1, Sx, Sy, out);
}